// Round 1
// baseline (21803.319 us; speedup 1.0000x reference)
//
#include <hip/hip_runtime.h>
#include <hip/hip_bf16.h>

#define NB 4
#define NS 1024
#define NIN 6
#define ND 512
#define NH 8
#define NLAYERS 4
#define NF 2048
#define NDK 64
#define LN_EPS 1e-5f

// ---------------- input projection: out = x @ W + b + pe ----------------
__global__ __launch_bounds__(256) void in_proj_kernel(
    const float* __restrict__ x, const float* __restrict__ W,
    const float* __restrict__ bias, const float* __restrict__ pe,
    float* __restrict__ out) {
    int idx = blockIdx.x * 256 + threadIdx.x;      // over B*S*D
    int d = idx & (ND - 1);
    int bs = idx / ND;
    int s = bs & (NS - 1);
    const float* xr = x + (size_t)bs * NIN;
    float acc = bias[d] + pe[(size_t)s * ND + d];
#pragma unroll
    for (int i = 0; i < NIN; ++i) acc += xr[i] * W[(size_t)i * ND + d];
    out[idx] = acc;
}

// ---------------- generic fp32 GEMM: C[M,N] = A[M,K] @ W[K,N] + bias (opt relu) ----
// BM=BN=64, BK=16, 256 threads, 4x4 microtile
template <int RELU>
__global__ __launch_bounds__(256) void gemm_kernel(
    const float* __restrict__ A, const float* __restrict__ W,
    const float* __restrict__ bias, float* __restrict__ C,
    int M, int N, int K) {
    __shared__ float As[16][64];
    __shared__ float Bs[16][64];
    int bm = blockIdx.y * 64, bn = blockIdx.x * 64;
    int tid = threadIdx.x;
    int tx = tid & 15, ty = tid >> 4;
    float acc[4][4] = {};
    for (int k0 = 0; k0 < K; k0 += 16) {
        {   // A tile (transposed into LDS)
            int row = tid >> 2, kq = (tid & 3) * 4;
            const float4 av = *reinterpret_cast<const float4*>(
                A + (size_t)(bm + row) * K + k0 + kq);
            As[kq + 0][row] = av.x; As[kq + 1][row] = av.y;
            As[kq + 2][row] = av.z; As[kq + 3][row] = av.w;
        }
        {   // W tile
            int k = tid >> 4, nq = (tid & 15) * 4;
            *reinterpret_cast<float4*>(&Bs[k][nq]) =
                *reinterpret_cast<const float4*>(W + (size_t)(k0 + k) * N + bn + nq);
        }
        __syncthreads();
#pragma unroll
        for (int kk = 0; kk < 16; ++kk) {
            float4 a4 = *reinterpret_cast<const float4*>(&As[kk][ty * 4]);
            float4 b4 = *reinterpret_cast<const float4*>(&Bs[kk][tx * 4]);
            float a[4] = {a4.x, a4.y, a4.z, a4.w};
            float b[4] = {b4.x, b4.y, b4.z, b4.w};
#pragma unroll
            for (int i = 0; i < 4; ++i)
#pragma unroll
                for (int j = 0; j < 4; ++j) acc[i][j] += a[i] * b[j];
        }
        __syncthreads();
    }
#pragma unroll
    for (int i = 0; i < 4; ++i) {
        int row = bm + ty * 4 + i;
        int col = bn + tx * 4;
        float4 bv = *reinterpret_cast<const float4*>(bias + col);
        float4 o;
        o.x = acc[i][0] + bv.x; o.y = acc[i][1] + bv.y;
        o.z = acc[i][2] + bv.z; o.w = acc[i][3] + bv.w;
        if (RELU) {
            o.x = fmaxf(o.x, 0.f); o.y = fmaxf(o.y, 0.f);
            o.z = fmaxf(o.z, 0.f); o.w = fmaxf(o.w, 0.f);
        }
        *reinterpret_cast<float4*>(C + (size_t)row * N + col) = o;
    }
}

// ---------------- residual + LayerNorm: out = LN(x + res)*g + b ----------------
__global__ __launch_bounds__(256) void ln_kernel(
    const float* __restrict__ x, const float* __restrict__ res,
    const float* __restrict__ g, const float* __restrict__ beta,
    float* __restrict__ out) {
    int row = blockIdx.x;
    int tid = threadIdx.x;
    const float* xr = x + (size_t)row * ND;
    const float* rr = res + (size_t)row * ND;
    float v0 = xr[tid] + rr[tid];
    float v1 = xr[tid + 256] + rr[tid + 256];
    float s = v0 + v1, sq = v0 * v0 + v1 * v1;
#pragma unroll
    for (int m = 1; m < 64; m <<= 1) { s += __shfl_xor(s, m); sq += __shfl_xor(sq, m); }
    __shared__ float ls[4], lq[4];
    int wid = tid >> 6, lane = tid & 63;
    if (lane == 0) { ls[wid] = s; lq[wid] = sq; }
    __syncthreads();
    s = ls[0] + ls[1] + ls[2] + ls[3];
    sq = lq[0] + lq[1] + lq[2] + lq[3];
    float mean = s * (1.f / ND);
    float var = sq * (1.f / ND) - mean * mean;
    float rstd = rsqrtf(var + LN_EPS);
    out[(size_t)row * ND + tid] = (v0 - mean) * rstd * g[tid] + beta[tid];
    out[(size_t)row * ND + tid + 256] = (v1 - mean) * rstd * g[tid + 256] + beta[tid + 256];
}

// ---------------- attention: per (b,h,8 q-rows) ----------------
// Q,K,V layout [B,S,D] with head h at columns h*64..h*64+63
__global__ __launch_bounds__(256) void attn_kernel(
    const float* __restrict__ Q, const float* __restrict__ K,
    const float* __restrict__ V, float* __restrict__ O) {
    __shared__ float sc[8][NS];     // 32 KB
    __shared__ float qs[8][NDK];    // 2 KB
    int qb = blockIdx.x * 8;
    int bh = blockIdx.y;
    int b = bh / NH, h = bh % NH;
    int tid = threadIdx.x;
    const size_t base = ((size_t)b * NS) * ND + (size_t)h * NDK;

    for (int i = tid; i < 8 * NDK; i += 256) {
        int r = i >> 6, d = i & 63;
        qs[r][d] = Q[base + (size_t)(qb + r) * ND + d];
    }
    __syncthreads();

    const float scale = 0.125f;  // 1/sqrt(64)
    // phase 1: scores. 8 rows x 1024 k = 32 iters of 256 threads
    for (int it = 0; it < 32; ++it) {
        int r = it >> 2;
        int k = ((it & 3) << 8) + tid;
        const float4* kp4 = reinterpret_cast<const float4*>(K + base + (size_t)k * ND);
        float acc = 0.f;
#pragma unroll
        for (int d4 = 0; d4 < NDK / 4; ++d4) {
            float4 kv = kp4[d4];
            acc += qs[r][4 * d4 + 0] * kv.x + qs[r][4 * d4 + 1] * kv.y
                 + qs[r][4 * d4 + 2] * kv.z + qs[r][4 * d4 + 3] * kv.w;
        }
        sc[r][k] = acc * scale;
    }
    __syncthreads();

    // phase 2: softmax, wave w handles rows 2w, 2w+1
    int wid = tid >> 6, lane = tid & 63;
#pragma unroll
    for (int rr = 0; rr < 2; ++rr) {
        int r = wid * 2 + rr;
        float mx = -1e30f;
        for (int k = lane; k < NS; k += 64) mx = fmaxf(mx, sc[r][k]);
#pragma unroll
        for (int m = 1; m < 64; m <<= 1) mx = fmaxf(mx, __shfl_xor(mx, m));
        float sum = 0.f;
        for (int k = lane; k < NS; k += 64) {
            float e = __expf(sc[r][k] - mx);
            sc[r][k] = e;
            sum += e;
        }
#pragma unroll
        for (int m = 1; m < 64; m <<= 1) sum += __shfl_xor(sum, m);
        float inv = 1.f / sum;
        for (int k = lane; k < NS; k += 64) sc[r][k] *= inv;
    }
    __syncthreads();

    // phase 3: ctx = attn @ V. thread: d = lane, rows r0 and r0+4
    int d = tid & 63;
    int r0 = tid >> 6;
    float acc0 = 0.f, acc1 = 0.f;
    const float* vp = V + base + d;
    for (int k = 0; k < NS; ++k) {
        float vv = vp[(size_t)k * ND];
        acc0 += sc[r0][k] * vv;
        acc1 += sc[r0 + 4][k] * vv;
    }
    O[base + (size_t)(qb + r0) * ND + d] = acc0;
    O[base + (size_t)(qb + r0 + 4) * ND + d] = acc1;
}

// ---------------- mean pool over seq, concat ----------------
__global__ __launch_bounds__(256) void pool_kernel(
    const float* __restrict__ Lb, const float* __restrict__ Rb,
    float* __restrict__ fused) {
    int idx = blockIdx.x * 256 + threadIdx.x;   // B * 2D = 4096
    int b = idx >> 10;
    int c = idx & 1023;
    const float* src = (c < ND) ? (Lb + ((size_t)b * NS) * ND + c)
                                : (Rb + ((size_t)b * NS) * ND + (c - ND));
    float s = 0.f;
    for (int t = 0; t < NS; ++t) s += src[(size_t)t * ND];
    fused[idx] = s * (1.f / NS);
}

// ---------------- head: logits = relu(fused @ w1 + b1) @ w2 + b2 ----------------
__global__ __launch_bounds__(256) void head_kernel(
    const float* __restrict__ fused,
    const float* __restrict__ w1, const float* __restrict__ b1,
    const float* __restrict__ w2, const float* __restrict__ b2,
    float* __restrict__ out) {
    int b = blockIdx.x;
    int tid = threadIdx.x;
    __shared__ float hidden[ND];
    const float* fr = fused + (size_t)b * (2 * ND);
    for (int j = tid; j < ND; j += 256) {
        float acc = b1[j];
        for (int k = 0; k < 2 * ND; ++k) acc += fr[k] * w1[(size_t)k * ND + j];
        hidden[j] = fmaxf(acc, 0.f);
    }
    __syncthreads();
    float p0 = 0.f, p1 = 0.f;
    for (int j = tid; j < ND; j += 256) {
        float hv = hidden[j];
        p0 += hv * w2[j * 2 + 0];
        p1 += hv * w2[j * 2 + 1];
    }
#pragma unroll
    for (int m = 1; m < 64; m <<= 1) { p0 += __shfl_xor(p0, m); p1 += __shfl_xor(p1, m); }
    __shared__ float r0s[4], r1s[4];
    int wid = tid >> 6, lane = tid & 63;
    if (lane == 0) { r0s[wid] = p0; r1s[wid] = p1; }
    __syncthreads();
    if (tid == 0) {
        out[b * 2 + 0] = r0s[0] + r0s[1] + r0s[2] + r0s[3] + b2[0];
        out[b * 2 + 1] = r1s[0] + r1s[1] + r1s[2] + r1s[3] + b2[1];
    }
}

extern "C" void kernel_launch(void* const* d_in, const int* in_sizes, int n_in,
                              void* d_out, int out_size, void* d_ws, size_t ws_size,
                              hipStream_t stream) {
    const float* left_wrist  = (const float*)d_in[0];
    const float* right_wrist = (const float*)d_in[1];
    const float* Wl = (const float*)d_in[2];
    const float* bl = (const float*)d_in[3];
    const float* Wr = (const float*)d_in[4];
    const float* br = (const float*)d_in[5];
    const float* pe = (const float*)d_in[6];
    const float* mha_w    = (const float*)d_in[7];   // [L,4,4,D,D]
    const float* mha_b    = (const float*)d_in[8];   // [L,4,4,D]
    const float* mha_ln_g = (const float*)d_in[9];   // [L,4,D]
    const float* mha_ln_b = (const float*)d_in[10];
    const float* ff_w1 = (const float*)d_in[11];     // [L,2,D,F]
    const float* ff_b1 = (const float*)d_in[12];     // [L,2,F]
    const float* ff_w2 = (const float*)d_in[13];     // [L,2,F,D]
    const float* ff_b2 = (const float*)d_in[14];     // [L,2,D]
    const float* ff_ln_g = (const float*)d_in[15];   // [L,2,D]
    const float* ff_ln_b = (const float*)d_in[16];
    const float* h1_w1 = (const float*)d_in[17];
    const float* h1_b1 = (const float*)d_in[18];
    const float* h1_w2 = (const float*)d_in[19];
    const float* h1_b2 = (const float*)d_in[20];
    const float* h2_w1 = (const float*)d_in[21];
    const float* h2_b1 = (const float*)d_in[22];
    const float* h2_w2 = (const float*)d_in[23];
    const float* h2_b2 = (const float*)d_in[24];
    float* out = (float*)d_out;

    float* ws = (float*)d_ws;
    const size_t NTOK = (size_t)NB * NS * ND;   // 2M floats
    float* Lb  = ws;
    float* Rb  = Lb + NTOK;
    float* LC  = Rb + NTOK;
    float* RC  = LC + NTOK;
    float* Qb  = RC + NTOK;
    float* Kb  = Qb + NTOK;
    float* Vb  = Kb + NTOK;
    float* CT  = Vb + NTOK;
    float* TMP = CT + NTOK;
    float* Hh  = TMP + NTOK;                    // B*S*F = 8M floats
    float* FUSED = Hh + (size_t)NB * NS * NF;   // B*2D

    const int M = NB * NS;  // 4096

    in_proj_kernel<<<(NB * NS * ND) / 256, 256, 0, stream>>>(left_wrist, Wl, bl, pe, Lb);
    in_proj_kernel<<<(NB * NS * ND) / 256, 256, 0, stream>>>(right_wrist, Wr, br, pe, Rb);

    auto GEMM = [&](const float* A, const float* W, const float* bias, float* C,
                    int N, int K, bool relu) {
        dim3 grid(N / 64, M / 64);
        if (relu) gemm_kernel<1><<<grid, 256, 0, stream>>>(A, W, bias, C, M, N, K);
        else      gemm_kernel<0><<<grid, 256, 0, stream>>>(A, W, bias, C, M, N, K);
    };

    for (int l = 0; l < NLAYERS; ++l) {
        auto MHA = [&](const float* qin, const float* kvin, int blk, float* outbuf) {
            const float* w  = mha_w + (((size_t)l * 4 + blk) * 4) * ND * ND;
            const float* bb = mha_b + (((size_t)l * 4 + blk) * 4) * ND;
            GEMM(qin,  w + 0 * (size_t)ND * ND, bb + 0 * ND, Qb, ND, ND, false);
            GEMM(kvin, w + 1 * (size_t)ND * ND, bb + 1 * ND, Kb, ND, ND, false);
            GEMM(kvin, w + 2 * (size_t)ND * ND, bb + 2 * ND, Vb, ND, ND, false);
            attn_kernel<<<dim3(NS / 8, NB * NH), 256, 0, stream>>>(Qb, Kb, Vb, CT);
            GEMM(CT, w + 3 * (size_t)ND * ND, bb + 3 * ND, TMP, ND, ND, false);
            const float* g  = mha_ln_g + ((size_t)l * 4 + blk) * ND;
            const float* be = mha_ln_b + ((size_t)l * 4 + blk) * ND;
            ln_kernel<<<M, 256, 0, stream>>>(TMP, qin, g, be, outbuf);
        };
        MHA(Lb, Rb, 0, LC);
        MHA(Rb, Lb, 1, RC);
        MHA(LC, LC, 2, Lb);
        MHA(RC, RC, 3, Rb);
        auto FFN = [&](float* X, int ch) {
            const float* w1 = ff_w1 + ((size_t)l * 2 + ch) * ND * NF;
            const float* b1 = ff_b1 + ((size_t)l * 2 + ch) * NF;
            const float* w2 = ff_w2 + ((size_t)l * 2 + ch) * NF * ND;
            const float* b2 = ff_b2 + ((size_t)l * 2 + ch) * ND;
            GEMM(X, w1, b1, Hh, NF, ND, true);
            GEMM(Hh, w2, b2, TMP, ND, NF, false);
            const float* g  = ff_ln_g + ((size_t)l * 2 + ch) * ND;
            const float* be = ff_ln_b + ((size_t)l * 2 + ch) * ND;
            ln_kernel<<<M, 256, 0, stream>>>(TMP, X, g, be, X);
        };
        FFN(Lb, 0);
        FFN(Rb, 1);
    }

    pool_kernel<<<(NB * 2 * ND) / 256, 256, 0, stream>>>(Lb, Rb, FUSED);
    head_kernel<<<NB, 256, 0, stream>>>(FUSED, h1_w1, h1_b1, h1_w2, h1_b2, out);
    head_kernel<<<NB, 256, 0, stream>>>(FUSED, h2_w1, h2_b1, h2_w2, h2_b2, out + NB * 2);
}

// Round 2
// 5663.882 us; speedup vs baseline: 3.8495x; 3.8495x over previous
//
#include <hip/hip_runtime.h>
#include <hip/hip_bf16.h>

#define NB 4
#define NS 1024
#define NIN 6
#define ND 512
#define NH 8
#define NLAYERS 4
#define NF 2048
#define NDK 64
#define LN_EPS 1e-5f

typedef unsigned short u16;
typedef __attribute__((ext_vector_type(4))) unsigned short u16x4;
typedef __attribute__((ext_vector_type(8))) short s16x8;     // 8 bf16 (4 VGPRs)
typedef __attribute__((ext_vector_type(4))) float f32x4;
typedef __attribute__((ext_vector_type(4))) unsigned int u32x4;

#define MFMA_BF16(A, B, C) __builtin_amdgcn_mfma_f32_16x16x32_bf16(A, B, C, 0, 0, 0)

__device__ inline u16 f2bf(float f) {
    unsigned int u = __builtin_bit_cast(unsigned int, f);
    u += 0x7fffu + ((u >> 16) & 1u);   // round-nearest-even
    return (u16)(u >> 16);
}

// ---------------- input projection: out = x @ W + b + pe ----------------
__global__ __launch_bounds__(256) void in_proj_kernel(
    const float* __restrict__ x, const float* __restrict__ W,
    const float* __restrict__ bias, const float* __restrict__ pe,
    float* __restrict__ out) {
    int idx = blockIdx.x * 256 + threadIdx.x;      // over B*S*D
    int d = idx & (ND - 1);
    int bs = idx / ND;
    int s = bs & (NS - 1);
    const float* xr = x + (size_t)bs * NIN;
    float acc = bias[d] + pe[(size_t)s * ND + d];
#pragma unroll
    for (int i = 0; i < NIN; ++i) acc += xr[i] * W[(size_t)i * ND + d];
    out[idx] = acc;
}

// ---------------- generic fp32 GEMM: C[M,N] = A[M,K] @ W[K,N] + bias ----------
// OMODE: 0 = fp32 out, 1 = bf16 out row-major, 2 = bf16 out transposed [B,H,DK,S]
template <int RELU, int OMODE>
__global__ __launch_bounds__(256) void gemm_kernel(
    const float* __restrict__ A, const float* __restrict__ W,
    const float* __restrict__ bias, void* __restrict__ Cv,
    int M, int N, int K) {
    __shared__ float As[16][64];
    __shared__ float Bs[16][64];
    int bm = blockIdx.y * 64, bn = blockIdx.x * 64;
    int tid = threadIdx.x;
    int tx = tid & 15, ty = tid >> 4;
    float acc[4][4] = {};
    for (int k0 = 0; k0 < K; k0 += 16) {
        {   // A tile (transposed into LDS)
            int row = tid >> 2, kq = (tid & 3) * 4;
            const float4 av = *reinterpret_cast<const float4*>(
                A + (size_t)(bm + row) * K + k0 + kq);
            As[kq + 0][row] = av.x; As[kq + 1][row] = av.y;
            As[kq + 2][row] = av.z; As[kq + 3][row] = av.w;
        }
        {   // W tile
            int k = tid >> 4, nq = (tid & 15) * 4;
            *reinterpret_cast<float4*>(&Bs[k][nq]) =
                *reinterpret_cast<const float4*>(W + (size_t)(k0 + k) * N + bn + nq);
        }
        __syncthreads();
#pragma unroll
        for (int kk = 0; kk < 16; ++kk) {
            float4 a4 = *reinterpret_cast<const float4*>(&As[kk][ty * 4]);
            float4 b4 = *reinterpret_cast<const float4*>(&Bs[kk][tx * 4]);
            float a[4] = {a4.x, a4.y, a4.z, a4.w};
            float b[4] = {b4.x, b4.y, b4.z, b4.w};
#pragma unroll
            for (int i = 0; i < 4; ++i)
#pragma unroll
                for (int j = 0; j < 4; ++j) acc[i][j] += a[i] * b[j];
        }
        __syncthreads();
    }
    int col = bn + tx * 4;
    float4 bv = *reinterpret_cast<const float4*>(bias + col);
    if (OMODE == 0 || OMODE == 1) {
#pragma unroll
        for (int i = 0; i < 4; ++i) {
            int row = bm + ty * 4 + i;
            float o0 = acc[i][0] + bv.x, o1 = acc[i][1] + bv.y;
            float o2 = acc[i][2] + bv.z, o3 = acc[i][3] + bv.w;
            if (RELU) {
                o0 = fmaxf(o0, 0.f); o1 = fmaxf(o1, 0.f);
                o2 = fmaxf(o2, 0.f); o3 = fmaxf(o3, 0.f);
            }
            if (OMODE == 0) {
                float4 o = {o0, o1, o2, o3};
                *reinterpret_cast<float4*>((float*)Cv + (size_t)row * N + col) = o;
            } else {
                u16x4 o = {f2bf(o0), f2bf(o1), f2bf(o2), f2bf(o3)};
                *reinterpret_cast<u16x4*>((u16*)Cv + (size_t)row * N + col) = o;
            }
        }
    } else {
        // transposed bf16: out[((b*NH + h)*NDK + dk)*NS + s], col = h*64+dk, row = b*NS+s
        int s0 = (bm + ty * 4) & (NS - 1);
        int bidx = (bm + ty * 4) >> 10;
        float bb[4] = {bv.x, bv.y, bv.z, bv.w};
#pragma unroll
        for (int j = 0; j < 4; ++j) {
            int c = col + j;
            int h = c >> 6, dk = c & 63;
            u16x4 o = {f2bf(acc[0][j] + bb[j]), f2bf(acc[1][j] + bb[j]),
                       f2bf(acc[2][j] + bb[j]), f2bf(acc[3][j] + bb[j])};
            *reinterpret_cast<u16x4*>((u16*)Cv +
                (((size_t)(bidx * NH + h) * NDK + dk) * NS + s0)) = o;
        }
    }
}

// ---------------- residual + LayerNorm: out = LN(x + res)*g + b ----------------
__global__ __launch_bounds__(256) void ln_kernel(
    const float* __restrict__ x, const float* __restrict__ res,
    const float* __restrict__ g, const float* __restrict__ beta,
    float* __restrict__ out) {
    int row = blockIdx.x;
    int tid = threadIdx.x;
    const float* xr = x + (size_t)row * ND;
    const float* rr = res + (size_t)row * ND;
    float v0 = xr[tid] + rr[tid];
    float v1 = xr[tid + 256] + rr[tid + 256];
    float s = v0 + v1, sq = v0 * v0 + v1 * v1;
#pragma unroll
    for (int m = 1; m < 64; m <<= 1) { s += __shfl_xor(s, m); sq += __shfl_xor(sq, m); }
    __shared__ float ls[4], lq[4];
    int wid = tid >> 6, lane = tid & 63;
    if (lane == 0) { ls[wid] = s; lq[wid] = sq; }
    __syncthreads();
    s = ls[0] + ls[1] + ls[2] + ls[3];
    sq = lq[0] + lq[1] + lq[2] + lq[3];
    float mean = s * (1.f / ND);
    float var = sq * (1.f / ND) - mean * mean;
    float rstd = rsqrtf(var + LN_EPS);
    out[(size_t)row * ND + tid] = (v0 - mean) * rstd * g[tid] + beta[tid];
    out[(size_t)row * ND + tid + 256] = (v1 - mean) * rstd * g[tid + 256] + beta[tid + 256];
}

// ---------------- flash attention, bf16 MFMA ----------------
// Q,K bf16 [B,S,D]; Vt bf16 [B,H,DK,S]; O fp32 [B,S,D]
// grid: (S/64, B*H); 256 threads = 4 waves; wave w owns q-rows qt*64+w*16 .. +15
__global__ __launch_bounds__(256) void attn_kernel(
    const u16* __restrict__ Qb, const u16* __restrict__ Kb,
    const u16* __restrict__ Vtb, float* __restrict__ O) {
    __shared__ u16 Ks[64 * 64];       // [kv][d] swizzled, 8 KB
    __shared__ u16 Vts[64 * 64];      // [d][kv] swizzled, 8 KB
    __shared__ u16 Ps[4][16 * 64];    // per-wave P [q][kv] swizzled, 8 KB

    const int tid = threadIdx.x;
    const int w = tid >> 6, lane = tid & 63;
    const int l15 = lane & 15, lhi = lane >> 4;
    const int bh = blockIdx.y;
    const int b = bh >> 3, h = bh & 7;
    const int qb = blockIdx.x * 64 + w * 16;

    // Q fragments (A-layout): lane holds Q[qb + l15][h*64 + sl*32 + lhi*8 + j]
    s16x8 qf[2];
    {
        const u16* qp = Qb + ((size_t)(b * NS) + qb + l15) * ND + h * NDK + lhi * 8;
        qf[0] = *reinterpret_cast<const s16x8*>(qp);
        qf[1] = *reinterpret_cast<const s16x8*>(qp + 32);
    }

    f32x4 o[4] = {f32x4{0.f, 0.f, 0.f, 0.f}, f32x4{0.f, 0.f, 0.f, 0.f},
                  f32x4{0.f, 0.f, 0.f, 0.f}, f32x4{0.f, 0.f, 0.f, 0.f}};
    float m[4] = {-1e30f, -1e30f, -1e30f, -1e30f};
    float lsum[4] = {0.f, 0.f, 0.f, 0.f};

    const u16* Kbase = Kb + ((size_t)(b * NS)) * ND + h * NDK;
    const u16* Vbase = Vtb + ((size_t)bh * NDK) * NS;

    for (int c = 0; c < NS / 64; ++c) {
        const int kv0 = c * 64;
        __syncthreads();   // previous chunk's compute done before overwriting LDS
#pragma unroll
        for (int ss = 0; ss < 2; ++ss) {
            int s = tid + ss * 256;          // 512 slots of 8 bf16
            int r = s >> 3, c8 = s & 7;
            u32x4 kv = *reinterpret_cast<const u32x4*>(
                Kbase + (size_t)(kv0 + r) * ND + c8 * 8);
            *reinterpret_cast<u32x4*>((char*)Ks +
                ((r * 128 + c8 * 16) ^ ((r & 7) << 4))) = kv;
            u32x4 vv = *reinterpret_cast<const u32x4*>(
                Vbase + (size_t)r * NS + kv0 + c8 * 8);
            *reinterpret_cast<u32x4*>((char*)Vts +
                ((r * 128 + c8 * 16) ^ ((r & 7) << 4))) = vv;
        }
        __syncthreads();

        // ---- S = Q @ K^T (16 q x 64 kv per wave) ----
        f32x4 sc[4] = {f32x4{0.f, 0.f, 0.f, 0.f}, f32x4{0.f, 0.f, 0.f, 0.f},
                       f32x4{0.f, 0.f, 0.f, 0.f}, f32x4{0.f, 0.f, 0.f, 0.f}};
#pragma unroll
        for (int sl = 0; sl < 2; ++sl) {
#pragma unroll
            for (int kb = 0; kb < 4; ++kb) {
                int krow = kb * 16 + l15;
                s16x8 kf = *reinterpret_cast<const s16x8*>((char*)Ks +
                    ((krow * 128 + sl * 64 + lhi * 16) ^ ((krow & 7) << 4)));
                sc[kb] = MFMA_BF16(qf[sl], kf, sc[kb]);
            }
        }
        // ---- online softmax (row = lhi*4 + r; 16 lanes of same lhi share row) ----
        float corr[4];
#pragma unroll
        for (int r = 0; r < 4; ++r) {
            float s0 = sc[0][r] * 0.125f, s1 = sc[1][r] * 0.125f;
            float s2 = sc[2][r] * 0.125f, s3 = sc[3][r] * 0.125f;
            float mx = fmaxf(fmaxf(s0, s1), fmaxf(s2, s3));
#pragma unroll
            for (int msk = 1; msk < 16; msk <<= 1) mx = fmaxf(mx, __shfl_xor(mx, msk));
            float mn = fmaxf(m[r], mx);
            corr[r] = __expf(m[r] - mn);
            m[r] = mn;
            float p0 = __expf(s0 - mn), p1 = __expf(s1 - mn);
            float p2 = __expf(s2 - mn), p3 = __expf(s3 - mn);
            sc[0][r] = p0; sc[1][r] = p1; sc[2][r] = p2; sc[3][r] = p3;
            float rs = p0 + p1 + p2 + p3;
#pragma unroll
            for (int msk = 1; msk < 16; msk <<= 1) rs += __shfl_xor(rs, msk);
            lsum[r] = lsum[r] * corr[r] + rs;
        }
        // ---- P -> bf16 -> per-wave LDS (swizzled) ----
#pragma unroll
        for (int r = 0; r < 4; ++r) {
            int row = lhi * 4 + r;
#pragma unroll
            for (int kb = 0; kb < 4; ++kb) {
                int col = kb * 16 + l15;
                *reinterpret_cast<u16*>((char*)(Ps[w]) +
                    ((row * 128 + col * 2) ^ ((row & 7) << 4))) = f2bf(sc[kb][r]);
            }
        }
        // ---- rescale O ----
#pragma unroll
        for (int db = 0; db < 4; ++db)
#pragma unroll
            for (int r = 0; r < 4; ++r) o[db][r] *= corr[r];
        // ---- P fragments (A-layout) + PV ----
        s16x8 pf[2];
#pragma unroll
        for (int sl = 0; sl < 2; ++sl)
            pf[sl] = *reinterpret_cast<const s16x8*>((char*)(Ps[w]) +
                ((l15 * 128 + sl * 64 + lhi * 16) ^ ((l15 & 7) << 4)));
#pragma unroll
        for (int sl = 0; sl < 2; ++sl) {
#pragma unroll
            for (int db = 0; db < 4; ++db) {
                int vr = db * 16 + l15;
                s16x8 vf = *reinterpret_cast<const s16x8*>((char*)Vts +
                    ((vr * 128 + sl * 64 + lhi * 16) ^ ((vr & 7) << 4)));
                o[db] = MFMA_BF16(pf[sl], vf, o[db]);
            }
        }
    }
    // ---- epilogue: O /= lsum ----
#pragma unroll
    for (int db = 0; db < 4; ++db) {
#pragma unroll
        for (int r = 0; r < 4; ++r) {
            int q = qb + lhi * 4 + r;
            O[((size_t)(b * NS) + q) * ND + h * NDK + db * 16 + l15] =
                o[db][r] / lsum[r];
        }
    }
}

// ---------------- mean pool over seq, concat ----------------
__global__ __launch_bounds__(256) void pool_kernel(
    const float* __restrict__ Lb, const float* __restrict__ Rb,
    float* __restrict__ fused) {
    int idx = blockIdx.x * 256 + threadIdx.x;   // B * 2D = 4096
    int b = idx >> 10;
    int c = idx & 1023;
    const float* src = (c < ND) ? (Lb + ((size_t)b * NS) * ND + c)
                                : (Rb + ((size_t)b * NS) * ND + (c - ND));
    float s = 0.f;
    for (int t = 0; t < NS; ++t) s += src[(size_t)t * ND];
    fused[idx] = s * (1.f / NS);
}

// ---------------- head: logits = relu(fused @ w1 + b1) @ w2 + b2 ----------------
__global__ __launch_bounds__(256) void head_kernel(
    const float* __restrict__ fused,
    const float* __restrict__ w1, const float* __restrict__ b1,
    const float* __restrict__ w2, const float* __restrict__ b2,
    float* __restrict__ out) {
    int b = blockIdx.x;
    int tid = threadIdx.x;
    __shared__ float hidden[ND];
    const float* fr = fused + (size_t)b * (2 * ND);
    for (int j = tid; j < ND; j += 256) {
        float acc = b1[j];
        for (int k = 0; k < 2 * ND; ++k) acc += fr[k] * w1[(size_t)k * ND + j];
        hidden[j] = fmaxf(acc, 0.f);
    }
    __syncthreads();
    float p0 = 0.f, p1 = 0.f;
    for (int j = tid; j < ND; j += 256) {
        float hv = hidden[j];
        p0 += hv * w2[j * 2 + 0];
        p1 += hv * w2[j * 2 + 1];
    }
#pragma unroll
    for (int m = 1; m < 64; m <<= 1) { p0 += __shfl_xor(p0, m); p1 += __shfl_xor(p1, m); }
    __shared__ float r0s[4], r1s[4];
    int wid = tid >> 6, lane = tid & 63;
    if (lane == 0) { r0s[wid] = p0; r1s[wid] = p1; }
    __syncthreads();
    if (tid == 0) {
        out[b * 2 + 0] = r0s[0] + r0s[1] + r0s[2] + r0s[3] + b2[0];
        out[b * 2 + 1] = r1s[0] + r1s[1] + r1s[2] + r1s[3] + b2[1];
    }
}

extern "C" void kernel_launch(void* const* d_in, const int* in_sizes, int n_in,
                              void* d_out, int out_size, void* d_ws, size_t ws_size,
                              hipStream_t stream) {
    const float* left_wrist  = (const float*)d_in[0];
    const float* right_wrist = (const float*)d_in[1];
    const float* Wl = (const float*)d_in[2];
    const float* bl = (const float*)d_in[3];
    const float* Wr = (const float*)d_in[4];
    const float* br = (const float*)d_in[5];
    const float* pe = (const float*)d_in[6];
    const float* mha_w    = (const float*)d_in[7];   // [L,4,4,D,D]
    const float* mha_b    = (const float*)d_in[8];   // [L,4,4,D]
    const float* mha_ln_g = (const float*)d_in[9];   // [L,4,D]
    const float* mha_ln_b = (const float*)d_in[10];
    const float* ff_w1 = (const float*)d_in[11];     // [L,2,D,F]
    const float* ff_b1 = (const float*)d_in[12];     // [L,2,F]
    const float* ff_w2 = (const float*)d_in[13];     // [L,2,F,D]
    const float* ff_b2 = (const float*)d_in[14];     // [L,2,D]
    const float* ff_ln_g = (const float*)d_in[15];   // [L,2,D]
    const float* ff_ln_b = (const float*)d_in[16];
    const float* h1_w1 = (const float*)d_in[17];
    const float* h1_b1 = (const float*)d_in[18];
    const float* h1_w2 = (const float*)d_in[19];
    const float* h1_b2 = (const float*)d_in[20];
    const float* h2_w1 = (const float*)d_in[21];
    const float* h2_b1 = (const float*)d_in[22];
    const float* h2_w2 = (const float*)d_in[23];
    const float* h2_b2 = (const float*)d_in[24];
    float* out = (float*)d_out;

    const size_t NTOK = (size_t)NB * NS * ND;   // 2M elements
    float* ws = (float*)d_ws;
    float* Lb  = ws;
    float* Rb  = Lb + NTOK;
    float* LC  = Rb + NTOK;
    float* RC  = LC + NTOK;
    float* CT  = RC + NTOK;
    float* TMP = CT + NTOK;
    float* Hh  = TMP + NTOK;                        // B*S*F = 8M floats
    float* FUSED = Hh + (size_t)NB * NS * NF;       // B*2D = 4096
    u16* Qbf  = (u16*)(FUSED + NB * 2 * ND);
    u16* Kbf  = Qbf + NTOK;
    u16* Vtbf = Kbf + NTOK;

    const int M = NB * NS;  // 4096

    in_proj_kernel<<<(NB * NS * ND) / 256, 256, 0, stream>>>(left_wrist, Wl, bl, pe, Lb);
    in_proj_kernel<<<(NB * NS * ND) / 256, 256, 0, stream>>>(right_wrist, Wr, br, pe, Rb);

    auto GEMM_F32 = [&](const float* A, const float* W, const float* bias, float* C,
                        int N, int K, bool relu) {
        dim3 grid(N / 64, M / 64);
        if (relu) gemm_kernel<1, 0><<<grid, 256, 0, stream>>>(A, W, bias, C, M, N, K);
        else      gemm_kernel<0, 0><<<grid, 256, 0, stream>>>(A, W, bias, C, M, N, K);
    };
    auto GEMM_BF = [&](const float* A, const float* W, const float* bias, u16* C,
                       int N, int K) {
        dim3 grid(N / 64, M / 64);
        gemm_kernel<0, 1><<<grid, 256, 0, stream>>>(A, W, bias, C, M, N, K);
    };
    auto GEMM_VT = [&](const float* A, const float* W, const float* bias, u16* C,
                       int N, int K) {
        dim3 grid(N / 64, M / 64);
        gemm_kernel<0, 2><<<grid, 256, 0, stream>>>(A, W, bias, C, M, N, K);
    };

    for (int l = 0; l < NLAYERS; ++l) {
        auto MHA = [&](const float* qin, const float* kvin, int blk, float* outbuf) {
            const float* w  = mha_w + (((size_t)l * 4 + blk) * 4) * ND * ND;
            const float* bb = mha_b + (((size_t)l * 4 + blk) * 4) * ND;
            GEMM_BF(qin,  w + 0 * (size_t)ND * ND, bb + 0 * ND, Qbf, ND, ND);
            GEMM_BF(kvin, w + 1 * (size_t)ND * ND, bb + 1 * ND, Kbf, ND, ND);
            GEMM_VT(kvin, w + 2 * (size_t)ND * ND, bb + 2 * ND, Vtbf, ND, ND);
            attn_kernel<<<dim3(NS / 64, NB * NH), 256, 0, stream>>>(Qbf, Kbf, Vtbf, CT);
            GEMM_F32(CT, w + 3 * (size_t)ND * ND, bb + 3 * ND, TMP, ND, ND, false);
            const float* g  = mha_ln_g + ((size_t)l * 4 + blk) * ND;
            const float* be = mha_ln_b + ((size_t)l * 4 + blk) * ND;
            ln_kernel<<<M, 256, 0, stream>>>(TMP, qin, g, be, outbuf);
        };
        MHA(Lb, Rb, 0, LC);
        MHA(Rb, Lb, 1, RC);
        MHA(LC, LC, 2, Lb);
        MHA(RC, RC, 3, Rb);
        auto FFN = [&](float* X, int ch) {
            const float* w1 = ff_w1 + ((size_t)l * 2 + ch) * ND * NF;
            const float* b1 = ff_b1 + ((size_t)l * 2 + ch) * NF;
            const float* w2 = ff_w2 + ((size_t)l * 2 + ch) * NF * ND;
            const float* b2 = ff_b2 + ((size_t)l * 2 + ch) * ND;
            GEMM_F32(X, w1, b1, Hh, NF, ND, true);
            GEMM_F32(Hh, w2, b2, TMP, ND, NF, false);
            const float* g  = ff_ln_g + ((size_t)l * 2 + ch) * ND;
            const float* be = ff_ln_b + ((size_t)l * 2 + ch) * ND;
            ln_kernel<<<M, 256, 0, stream>>>(TMP, X, g, be, X);
        };
        FFN(Lb, 0);
        FFN(Rb, 1);
    }

    pool_kernel<<<(NB * 2 * ND) / 256, 256, 0, stream>>>(Lb, Rb, FUSED);
    head_kernel<<<NB, 256, 0, stream>>>(FUSED, h1_w1, h1_b1, h1_w2, h1_b2, out);
    head_kernel<<<NB, 256, 0, stream>>>(FUSED, h2_w1, h2_b1, h2_w2, h2_b2, out + NB * 2);
}

// Round 3
// 2102.587 us; speedup vs baseline: 10.3698x; 2.6938x over previous
//
#include <hip/hip_runtime.h>
#include <hip/hip_bf16.h>

#define NB 4
#define NS 1024
#define NIN 6
#define ND 512
#define NH 8
#define NLAYERS 4
#define NF 2048
#define NDK 64
#define LN_EPS 1e-5f

typedef unsigned short u16;
typedef __attribute__((ext_vector_type(4))) unsigned short u16x4;
typedef __attribute__((ext_vector_type(8))) short s16x8;     // 8 bf16 (4 VGPRs)
typedef __attribute__((ext_vector_type(4))) float f32x4;
typedef __attribute__((ext_vector_type(4))) unsigned int u32x4;

#define MFMA_BF16(A, B, C) __builtin_amdgcn_mfma_f32_16x16x32_bf16(A, B, C, 0, 0, 0)

#define GLOAD_LDS16(gsrc, ldst)                                                  \
    __builtin_amdgcn_global_load_lds(                                            \
        (const __attribute__((address_space(1))) void*)(gsrc),                   \
        (__attribute__((address_space(3))) void*)(ldst), 16, 0, 0)

__device__ inline u16 f2bf(float f) {
    unsigned int u = __builtin_bit_cast(unsigned int, f);
    u += 0x7fffu + ((u >> 16) & 1u);   // round-nearest-even
    return (u16)(u >> 16);
}

// ---------------- weight prep: W[K,N] f32 -> Wt[N,K] bf16 (batched via z) ------
__global__ __launch_bounds__(256) void transpose_kernel(
    const float* __restrict__ src, u16* __restrict__ dst, int K, int N) {
    __shared__ u16 t[64][72];
    const int tid = threadIdx.x;
    src += (size_t)blockIdx.z * K * N;
    dst += (size_t)blockIdx.z * K * N;
    const int n0 = blockIdx.x * 64, k0 = blockIdx.y * 64;
    {
        int r = tid >> 2, cq = (tid & 3) * 16;
        const float* sp = src + (size_t)(k0 + r) * N + n0 + cq;
#pragma unroll
        for (int q = 0; q < 4; ++q) {
            float4 v = *reinterpret_cast<const float4*>(sp + q * 4);
            t[r][cq + q * 4 + 0] = f2bf(v.x);
            t[r][cq + q * 4 + 1] = f2bf(v.y);
            t[r][cq + q * 4 + 2] = f2bf(v.z);
            t[r][cq + q * 4 + 3] = f2bf(v.w);
        }
    }
    __syncthreads();
    {
        int rn = tid >> 2, cq = (tid & 3) * 16;
        s16x8 o0, o1;
#pragma unroll
        for (int j = 0; j < 8; ++j) o0[j] = (short)t[cq + j][rn];
#pragma unroll
        for (int j = 0; j < 8; ++j) o1[j] = (short)t[cq + 8 + j][rn];
        u16* dp = dst + (size_t)(n0 + rn) * K + k0 + cq;
        *reinterpret_cast<s16x8*>(dp) = o0;
        *reinterpret_cast<s16x8*>(dp + 8) = o1;
    }
}

// ---------------- input projection: out = x @ W + b + pe (f32 + bf16 mirror) ---
__global__ __launch_bounds__(256) void in_proj_kernel(
    const float* __restrict__ x, const float* __restrict__ W,
    const float* __restrict__ bias, const float* __restrict__ pe,
    float* __restrict__ out, u16* __restrict__ outb) {
    int idx = blockIdx.x * 256 + threadIdx.x;      // over B*S*D
    int d = idx & (ND - 1);
    int bs = idx / ND;
    int s = bs & (NS - 1);
    const float* xr = x + (size_t)bs * NIN;
    float acc = bias[d] + pe[(size_t)s * ND + d];
#pragma unroll
    for (int i = 0; i < NIN; ++i) acc += xr[i] * W[(size_t)i * ND + d];
    out[idx] = acc;
    outb[idx] = f2bf(acc);
}

// ---------------- bf16 MFMA GEMM: C[M,N] = A[M,K] @ Wt[N,K]^T + bias ----------
// OMODE: 0 f32 out; 1 bf16 out + relu; 2 bf16 out; 3 bf16 out transposed [B,H,DK,S]
// BM=128, BK=64, 256 threads = 4 waves (2x2), wave computes 64 x (BN/2)
template <int OMODE, int BN>
__global__ __launch_bounds__(256) void bgemm_kernel(
    const u16* __restrict__ A, const u16* __restrict__ Wt,
    const float* __restrict__ bias, void* __restrict__ Cv,
    int M, int N, int K) {
    constexpr int WCOLS = BN / 2;
    constexpr int NT = WCOLS / 16;      // 4 (BN=128) or 2 (BN=64)
    constexpr int ASZ = 128 * 128;      // bytes per A buffer
    constexpr int BSZ = BN * 128;
    __shared__ char lds[2 * ASZ + 2 * BSZ];

    const int tid = threadIdx.x, wid = tid >> 6, lane = tid & 63;
    const int l15 = lane & 15, lhi = lane >> 4;
    const int wr = wid >> 1, wc = wid & 1;
    const int bm = blockIdx.y * 128, bn = blockIdx.x * BN;

    auto stage = [&](int buf, int k0) {
#pragma unroll
        for (int i = 0; i < 4; ++i) {
            int slot = (wid * 4 + i) * 64 + lane;
            int r = slot >> 3, p = slot & 7;
            const char* src = (const char*)(A + (size_t)(bm + r) * K + k0)
                              + ((p * 16) ^ ((r & 7) << 4));
            GLOAD_LDS16(src, lds + buf * ASZ + (wid * 4 + i) * 1024);
        }
#pragma unroll
        for (int i = 0; i < BN / 32; ++i) {
            int slot = (wid * (BN / 32) + i) * 64 + lane;
            int r = slot >> 3, p = slot & 7;
            const char* src = (const char*)(Wt + (size_t)(bn + r) * K + k0)
                              + ((p * 16) ^ ((r & 7) << 4));
            GLOAD_LDS16(src, lds + 2 * ASZ + buf * BSZ + (wid * (BN / 32) + i) * 1024);
        }
    };

    f32x4 acc[4][NT];
#pragma unroll
    for (int mt = 0; mt < 4; ++mt)
#pragma unroll
        for (int nt = 0; nt < NT; ++nt) acc[mt][nt] = f32x4{0.f, 0.f, 0.f, 0.f};

    const int KT = K >> 6;
    stage(0, 0);
    __syncthreads();
    for (int t = 0; t < KT; ++t) {
        if (t + 1 < KT) stage((t + 1) & 1, (t + 1) << 6);
        const char* Ab = lds + (t & 1) * ASZ;
        const char* Bb = lds + 2 * ASZ + (t & 1) * BSZ;
#pragma unroll
        for (int sl = 0; sl < 2; ++sl) {
            s16x8 af[4];
#pragma unroll
            for (int mt = 0; mt < 4; ++mt) {
                int row = wr * 64 + mt * 16 + l15;
                af[mt] = *reinterpret_cast<const s16x8*>(
                    Ab + ((row * 128 + sl * 64 + lhi * 16) ^ ((row & 7) << 4)));
            }
            s16x8 bfr[NT];
#pragma unroll
            for (int nt = 0; nt < NT; ++nt) {
                int row = wc * WCOLS + nt * 16 + l15;
                bfr[nt] = *reinterpret_cast<const s16x8*>(
                    Bb + ((row * 128 + sl * 64 + lhi * 16) ^ ((row & 7) << 4)));
            }
#pragma unroll
            for (int mt = 0; mt < 4; ++mt)
#pragma unroll
                for (int nt = 0; nt < NT; ++nt)
                    acc[mt][nt] = MFMA_BF16(af[mt], bfr[nt], acc[mt][nt]);
        }
        __syncthreads();
    }

    float bv[NT];
#pragma unroll
    for (int nt = 0; nt < NT; ++nt) bv[nt] = bias[bn + wc * WCOLS + nt * 16 + l15];

    if (OMODE == 0) {
        float* C = (float*)Cv;
#pragma unroll
        for (int mt = 0; mt < 4; ++mt) {
            int m0 = bm + wr * 64 + mt * 16 + lhi * 4;
#pragma unroll
            for (int nt = 0; nt < NT; ++nt) {
                int n = bn + wc * WCOLS + nt * 16 + l15;
#pragma unroll
                for (int r = 0; r < 4; ++r)
                    C[(size_t)(m0 + r) * N + n] = acc[mt][nt][r] + bv[nt];
            }
        }
    } else if (OMODE == 1 || OMODE == 2) {
        u16* C = (u16*)Cv;
#pragma unroll
        for (int mt = 0; mt < 4; ++mt) {
            int m0 = bm + wr * 64 + mt * 16 + lhi * 4;
#pragma unroll
            for (int nt = 0; nt < NT; ++nt) {
                int n = bn + wc * WCOLS + nt * 16 + l15;
#pragma unroll
                for (int r = 0; r < 4; ++r) {
                    float v = acc[mt][nt][r] + bv[nt];
                    if (OMODE == 1) v = fmaxf(v, 0.f);
                    C[(size_t)(m0 + r) * N + n] = f2bf(v);
                }
            }
        }
    } else {
        // transposed bf16: Vt[((b*NH + h)*NDK + dk)*NS + s]
        u16* C = (u16*)Cv;
#pragma unroll
        for (int mt = 0; mt < 4; ++mt) {
            int m0 = bm + wr * 64 + mt * 16 + lhi * 4;
            int b = m0 >> 10, s = m0 & (NS - 1);
#pragma unroll
            for (int nt = 0; nt < NT; ++nt) {
                int n = bn + wc * WCOLS + nt * 16 + l15;
                int h = n >> 6, dk = n & 63;
                u16x4 o = {f2bf(acc[mt][nt][0] + bv[nt]), f2bf(acc[mt][nt][1] + bv[nt]),
                           f2bf(acc[mt][nt][2] + bv[nt]), f2bf(acc[mt][nt][3] + bv[nt])};
                *reinterpret_cast<u16x4*>(C + ((size_t)((b * NH + h) * NDK + dk)) * NS + s) = o;
            }
        }
    }
}

// ---------------- residual + LayerNorm (f32 out + bf16 mirror) ----------------
__global__ __launch_bounds__(256) void ln_kernel(
    const float* __restrict__ x, const float* __restrict__ res,
    const float* __restrict__ g, const float* __restrict__ beta,
    float* __restrict__ out, u16* __restrict__ outb) {
    int row = blockIdx.x;
    int tid = threadIdx.x;
    const float* xr = x + (size_t)row * ND;
    const float* rr = res + (size_t)row * ND;
    float v0 = xr[tid] + rr[tid];
    float v1 = xr[tid + 256] + rr[tid + 256];
    float s = v0 + v1, sq = v0 * v0 + v1 * v1;
#pragma unroll
    for (int m = 1; m < 64; m <<= 1) { s += __shfl_xor(s, m); sq += __shfl_xor(sq, m); }
    __shared__ float ls[4], lq[4];
    int wid = tid >> 6, lane = tid & 63;
    if (lane == 0) { ls[wid] = s; lq[wid] = sq; }
    __syncthreads();
    s = ls[0] + ls[1] + ls[2] + ls[3];
    sq = lq[0] + lq[1] + lq[2] + lq[3];
    float mean = s * (1.f / ND);
    float var = sq * (1.f / ND) - mean * mean;
    float rstd = rsqrtf(var + LN_EPS);
    float o0 = (v0 - mean) * rstd * g[tid] + beta[tid];
    float o1 = (v1 - mean) * rstd * g[tid + 256] + beta[tid + 256];
    out[(size_t)row * ND + tid] = o0;
    out[(size_t)row * ND + tid + 256] = o1;
    outb[(size_t)row * ND + tid] = f2bf(o0);
    outb[(size_t)row * ND + tid + 256] = f2bf(o1);
}

// ---------------- flash attention, bf16 MFMA ----------------
// Q,K bf16 [B,S,D]; Vt bf16 [B,H,DK,S]; O bf16 [B,S,D]
__global__ __launch_bounds__(256) void attn_kernel(
    const u16* __restrict__ Qb, const u16* __restrict__ Kb,
    const u16* __restrict__ Vtb, u16* __restrict__ O) {
    __shared__ u16 Ks[64 * 64];       // [kv][d] swizzled, 8 KB
    __shared__ u16 Vts[64 * 64];      // [d][kv] swizzled, 8 KB
    __shared__ u16 Ps[4][16 * 64];    // per-wave P [q][kv] swizzled, 8 KB

    const int tid = threadIdx.x;
    const int w = tid >> 6, lane = tid & 63;
    const int l15 = lane & 15, lhi = lane >> 4;
    const int bh = blockIdx.y;
    const int b = bh >> 3, h = bh & 7;
    const int qb = blockIdx.x * 64 + w * 16;

    s16x8 qf[2];
    {
        const u16* qp = Qb + ((size_t)(b * NS) + qb + l15) * ND + h * NDK + lhi * 8;
        qf[0] = *reinterpret_cast<const s16x8*>(qp);
        qf[1] = *reinterpret_cast<const s16x8*>(qp + 32);
    }

    f32x4 o[4] = {f32x4{0.f, 0.f, 0.f, 0.f}, f32x4{0.f, 0.f, 0.f, 0.f},
                  f32x4{0.f, 0.f, 0.f, 0.f}, f32x4{0.f, 0.f, 0.f, 0.f}};
    float m[4] = {-1e30f, -1e30f, -1e30f, -1e30f};
    float lsum[4] = {0.f, 0.f, 0.f, 0.f};

    const u16* Kbase = Kb + ((size_t)(b * NS)) * ND + h * NDK;
    const u16* Vbase = Vtb + ((size_t)bh * NDK) * NS;

    for (int c = 0; c < NS / 64; ++c) {
        const int kv0 = c * 64;
        __syncthreads();
#pragma unroll
        for (int ss = 0; ss < 2; ++ss) {
            int s = tid + ss * 256;          // 512 slots of 8 bf16
            int r = s >> 3, c8 = s & 7;
            u32x4 kv = *reinterpret_cast<const u32x4*>(
                Kbase + (size_t)(kv0 + r) * ND + c8 * 8);
            *reinterpret_cast<u32x4*>((char*)Ks +
                ((r * 128 + c8 * 16) ^ ((r & 7) << 4))) = kv;
            u32x4 vv = *reinterpret_cast<const u32x4*>(
                Vbase + (size_t)r * NS + kv0 + c8 * 8);
            *reinterpret_cast<u32x4*>((char*)Vts +
                ((r * 128 + c8 * 16) ^ ((r & 7) << 4))) = vv;
        }
        __syncthreads();

        f32x4 sc[4] = {f32x4{0.f, 0.f, 0.f, 0.f}, f32x4{0.f, 0.f, 0.f, 0.f},
                       f32x4{0.f, 0.f, 0.f, 0.f}, f32x4{0.f, 0.f, 0.f, 0.f}};
#pragma unroll
        for (int sl = 0; sl < 2; ++sl) {
#pragma unroll
            for (int kb = 0; kb < 4; ++kb) {
                int krow = kb * 16 + l15;
                s16x8 kf = *reinterpret_cast<const s16x8*>((char*)Ks +
                    ((krow * 128 + sl * 64 + lhi * 16) ^ ((krow & 7) << 4)));
                sc[kb] = MFMA_BF16(qf[sl], kf, sc[kb]);
            }
        }
        float corr[4];
#pragma unroll
        for (int r = 0; r < 4; ++r) {
            float s0 = sc[0][r] * 0.125f, s1 = sc[1][r] * 0.125f;
            float s2 = sc[2][r] * 0.125f, s3 = sc[3][r] * 0.125f;
            float mx = fmaxf(fmaxf(s0, s1), fmaxf(s2, s3));
#pragma unroll
            for (int msk = 1; msk < 16; msk <<= 1) mx = fmaxf(mx, __shfl_xor(mx, msk));
            float mn = fmaxf(m[r], mx);
            corr[r] = __expf(m[r] - mn);
            m[r] = mn;
            float p0 = __expf(s0 - mn), p1 = __expf(s1 - mn);
            float p2 = __expf(s2 - mn), p3 = __expf(s3 - mn);
            sc[0][r] = p0; sc[1][r] = p1; sc[2][r] = p2; sc[3][r] = p3;
            float rs = p0 + p1 + p2 + p3;
#pragma unroll
            for (int msk = 1; msk < 16; msk <<= 1) rs += __shfl_xor(rs, msk);
            lsum[r] = lsum[r] * corr[r] + rs;
        }
#pragma unroll
        for (int r = 0; r < 4; ++r) {
            int row = lhi * 4 + r;
#pragma unroll
            for (int kb = 0; kb < 4; ++kb) {
                int col = kb * 16 + l15;
                *reinterpret_cast<u16*>((char*)(Ps[w]) +
                    ((row * 128 + col * 2) ^ ((row & 7) << 4))) = f2bf(sc[kb][r]);
            }
        }
#pragma unroll
        for (int db = 0; db < 4; ++db)
#pragma unroll
            for (int r = 0; r < 4; ++r) o[db][r] *= corr[r];
        s16x8 pf[2];
#pragma unroll
        for (int sl = 0; sl < 2; ++sl)
            pf[sl] = *reinterpret_cast<const s16x8*>((char*)(Ps[w]) +
                ((l15 * 128 + sl * 64 + lhi * 16) ^ ((l15 & 7) << 4)));
#pragma unroll
        for (int sl = 0; sl < 2; ++sl) {
#pragma unroll
            for (int db = 0; db < 4; ++db) {
                int vr = db * 16 + l15;
                s16x8 vf = *reinterpret_cast<const s16x8*>((char*)Vts +
                    ((vr * 128 + sl * 64 + lhi * 16) ^ ((vr & 7) << 4)));
                o[db] = MFMA_BF16(pf[sl], vf, o[db]);
            }
        }
    }
#pragma unroll
    for (int db = 0; db < 4; ++db) {
#pragma unroll
        for (int r = 0; r < 4; ++r) {
            int q = qb + lhi * 4 + r;
            O[((size_t)(b * NS) + q) * ND + h * NDK + db * 16 + l15] =
                f2bf(o[db][r] / lsum[r]);
        }
    }
}

// ---------------- mean pool over seq, concat ----------------
__global__ __launch_bounds__(256) void pool_kernel(
    const float* __restrict__ Lb, const float* __restrict__ Rb,
    float* __restrict__ fused) {
    int idx = blockIdx.x * 256 + threadIdx.x;   // B * 2D = 4096
    int b = idx >> 10;
    int c = idx & 1023;
    const float* src = (c < ND) ? (Lb + ((size_t)b * NS) * ND + c)
                                : (Rb + ((size_t)b * NS) * ND + (c - ND));
    float s = 0.f;
    for (int t = 0; t < NS; ++t) s += src[(size_t)t * ND];
    fused[idx] = s * (1.f / NS);
}

// ---------------- head: logits = relu(fused @ w1 + b1) @ w2 + b2 ----------------
__global__ __launch_bounds__(256) void head_kernel(
    const float* __restrict__ fused,
    const float* __restrict__ w1, const float* __restrict__ b1,
    const float* __restrict__ w2, const float* __restrict__ b2,
    float* __restrict__ out) {
    int b = blockIdx.x;
    int tid = threadIdx.x;
    __shared__ float hidden[ND];
    const float* fr = fused + (size_t)b * (2 * ND);
    for (int j = tid; j < ND; j += 256) {
        float acc = b1[j];
        for (int k = 0; k < 2 * ND; ++k) acc += fr[k] * w1[(size_t)k * ND + j];
        hidden[j] = fmaxf(acc, 0.f);
    }
    __syncthreads();
    float p0 = 0.f, p1 = 0.f;
    for (int j = tid; j < ND; j += 256) {
        float hv = hidden[j];
        p0 += hv * w2[j * 2 + 0];
        p1 += hv * w2[j * 2 + 1];
    }
#pragma unroll
    for (int m = 1; m < 64; m <<= 1) { p0 += __shfl_xor(p0, m); p1 += __shfl_xor(p1, m); }
    __shared__ float r0s[4], r1s[4];
    int wid = tid >> 6, lane = tid & 63;
    if (lane == 0) { r0s[wid] = p0; r1s[wid] = p1; }
    __syncthreads();
    if (tid == 0) {
        out[b * 2 + 0] = r0s[0] + r0s[1] + r0s[2] + r0s[3] + b2[0];
        out[b * 2 + 1] = r1s[0] + r1s[1] + r1s[2] + r1s[3] + b2[1];
    }
}

extern "C" void kernel_launch(void* const* d_in, const int* in_sizes, int n_in,
                              void* d_out, int out_size, void* d_ws, size_t ws_size,
                              hipStream_t stream) {
    const float* left_wrist  = (const float*)d_in[0];
    const float* right_wrist = (const float*)d_in[1];
    const float* Wl = (const float*)d_in[2];
    const float* bl = (const float*)d_in[3];
    const float* Wr = (const float*)d_in[4];
    const float* br = (const float*)d_in[5];
    const float* pe = (const float*)d_in[6];
    const float* mha_w    = (const float*)d_in[7];   // [L,4,4,D,D]
    const float* mha_b    = (const float*)d_in[8];   // [L,4,4,D]
    const float* mha_ln_g = (const float*)d_in[9];   // [L,4,D]
    const float* mha_ln_b = (const float*)d_in[10];
    const float* ff_w1 = (const float*)d_in[11];     // [L,2,D,F]
    const float* ff_b1 = (const float*)d_in[12];     // [L,2,F]
    const float* ff_w2 = (const float*)d_in[13];     // [L,2,F,D]
    const float* ff_b2 = (const float*)d_in[14];     // [L,2,D]
    const float* ff_ln_g = (const float*)d_in[15];   // [L,2,D]
    const float* ff_ln_b = (const float*)d_in[16];
    const float* h1_w1 = (const float*)d_in[17];
    const float* h1_b1 = (const float*)d_in[18];
    const float* h1_w2 = (const float*)d_in[19];
    const float* h1_b2 = (const float*)d_in[20];
    const float* h2_w1 = (const float*)d_in[21];
    const float* h2_b1 = (const float*)d_in[22];
    const float* h2_w2 = (const float*)d_in[23];
    const float* h2_b2 = (const float*)d_in[24];
    float* out = (float*)d_out;

    const size_t NTOK = (size_t)NB * NS * ND;   // 2M elements
    float* ws = (float*)d_ws;
    float* Lb  = ws;                 // f32 residual stream
    float* Rb  = Lb + NTOK;
    float* LC  = Rb + NTOK;
    float* RC  = LC + NTOK;
    float* TMP = RC + NTOK;
    float* FUSED = TMP + NTOK;       // 4096
    u16* Lbf  = (u16*)(FUSED + NB * 2 * ND);
    u16* Rbf  = Lbf + NTOK;
    u16* LCbf = Rbf + NTOK;
    u16* RCbf = LCbf + NTOK;
    u16* Qbf  = RCbf + NTOK;
    u16* Kbf  = Qbf + NTOK;
    u16* Vtbf = Kbf + NTOK;
    u16* CTbf = Vtbf + NTOK;
    u16* Hh   = CTbf + NTOK;                        // B*S*F
    u16* WtM  = Hh + (size_t)NB * NS * NF;          // 64 x [512,512]
    u16* WtF1 = WtM + (size_t)64 * ND * ND;         // 8 x [2048,512]
    u16* WtF2 = WtF1 + (size_t)8 * ND * NF;         // 8 x [512,2048]

    const int M = NB * NS;  // 4096

    // ---- weight prep (every launch; graph-safe) ----
    transpose_kernel<<<dim3(ND / 64, ND / 64, 64), 256, 0, stream>>>(mha_w, WtM, ND, ND);
    transpose_kernel<<<dim3(NF / 64, ND / 64, 8), 256, 0, stream>>>(ff_w1, WtF1, ND, NF);
    transpose_kernel<<<dim3(ND / 64, NF / 64, 8), 256, 0, stream>>>(ff_w2, WtF2, NF, ND);

    in_proj_kernel<<<(NB * NS * ND) / 256, 256, 0, stream>>>(left_wrist, Wl, bl, pe, Lb, Lbf);
    in_proj_kernel<<<(NB * NS * ND) / 256, 256, 0, stream>>>(right_wrist, Wr, br, pe, Rb, Rbf);

    for (int l = 0; l < NLAYERS; ++l) {
        auto MHA = [&](const float* qin, const u16* qin_bf, const u16* kvin_bf,
                       int blk, float* outf, u16* outbf) {
            const u16* wt = WtM + (((size_t)l * 4 + blk) * 4) * ND * ND;
            const float* bb = mha_b + (((size_t)l * 4 + blk) * 4) * ND;
            bgemm_kernel<2, 64><<<dim3(ND / 64, M / 128), 256, 0, stream>>>(
                qin_bf, wt + 0 * (size_t)ND * ND, bb + 0 * ND, Qbf, M, ND, ND);
            bgemm_kernel<2, 64><<<dim3(ND / 64, M / 128), 256, 0, stream>>>(
                kvin_bf, wt + 1 * (size_t)ND * ND, bb + 1 * ND, Kbf, M, ND, ND);
            bgemm_kernel<3, 64><<<dim3(ND / 64, M / 128), 256, 0, stream>>>(
                kvin_bf, wt + 2 * (size_t)ND * ND, bb + 2 * ND, Vtbf, M, ND, ND);
            attn_kernel<<<dim3(NS / 64, NB * NH), 256, 0, stream>>>(Qbf, Kbf, Vtbf, CTbf);
            bgemm_kernel<0, 64><<<dim3(ND / 64, M / 128), 256, 0, stream>>>(
                CTbf, wt + 3 * (size_t)ND * ND, bb + 3 * ND, TMP, M, ND, ND);
            const float* g  = mha_ln_g + ((size_t)l * 4 + blk) * ND;
            const float* be = mha_ln_b + ((size_t)l * 4 + blk) * ND;
            ln_kernel<<<M, 256, 0, stream>>>(TMP, qin, g, be, outf, outbf);
        };
        MHA(Lb, Lbf, Rbf, 0, LC, LCbf);
        MHA(Rb, Rbf, Lbf, 1, RC, RCbf);
        MHA(LC, LCbf, LCbf, 2, Lb, Lbf);
        MHA(RC, RCbf, RCbf, 3, Rb, Rbf);
        auto FFN = [&](float* Xf, u16* Xbf, int ch) {
            const u16* w1t = WtF1 + ((size_t)l * 2 + ch) * ND * NF;
            const float* b1 = ff_b1 + ((size_t)l * 2 + ch) * NF;
            const u16* w2t = WtF2 + ((size_t)l * 2 + ch) * NF * ND;
            const float* b2 = ff_b2 + ((size_t)l * 2 + ch) * ND;
            bgemm_kernel<1, 128><<<dim3(NF / 128, M / 128), 256, 0, stream>>>(
                Xbf, w1t, b1, Hh, M, NF, ND);
            bgemm_kernel<0, 64><<<dim3(ND / 64, M / 128), 256, 0, stream>>>(
                Hh, w2t, b2, TMP, M, ND, NF);
            const float* g  = ff_ln_g + ((size_t)l * 2 + ch) * ND;
            const float* be = ff_ln_b + ((size_t)l * 2 + ch) * ND;
            ln_kernel<<<M, 256, 0, stream>>>(TMP, Xf, g, be, Xf, Xbf);
        };
        FFN(Lb, Lbf, 0);
        FFN(Rb, Rbf, 1);
    }

    pool_kernel<<<(NB * 2 * ND) / 256, 256, 0, stream>>>(Lb, Rb, FUSED);
    head_kernel<<<NB, 256, 0, stream>>>(FUSED, h1_w1, h1_b1, h1_w2, h1_b2, out);
    head_kernel<<<NB, 256, 0, stream>>>(FUSED, h2_w1, h2_b1, h2_w2, h2_b2, out + NB * 2);
}

// Round 4
// 1479.835 us; speedup vs baseline: 14.7336x; 1.4208x over previous
//
#include <hip/hip_runtime.h>
#include <hip/hip_bf16.h>

#define NB 4
#define NS 1024
#define NIN 6
#define ND 512
#define NH 8
#define NLAYERS 4
#define NF 2048
#define NDK 64
#define LN_EPS 1e-5f

typedef unsigned short u16;
typedef __attribute__((ext_vector_type(4))) unsigned short u16x4;
typedef __attribute__((ext_vector_type(8))) short s16x8;     // 8 bf16 (4 VGPRs)
typedef __attribute__((ext_vector_type(4))) float f32x4;
typedef __attribute__((ext_vector_type(4))) unsigned int u32x4;

#define MFMA_BF16(A, B, C) __builtin_amdgcn_mfma_f32_16x16x32_bf16(A, B, C, 0, 0, 0)

#define GLOAD_LDS16(gsrc, ldst)                                                  \
    __builtin_amdgcn_global_load_lds(                                            \
        (const __attribute__((address_space(1))) void*)(gsrc),                   \
        (__attribute__((address_space(3))) void*)(ldst), 16, 0, 0)

__device__ inline u16 f2bf(float f) {
    unsigned int u = __builtin_bit_cast(unsigned int, f);
    u += 0x7fffu + ((u >> 16) & 1u);   // round-nearest-even
    return (u16)(u >> 16);
}

// ---------------- weight prep: W[K,N] f32 -> Wt[N,K] bf16 (batched via z) ------
__global__ __launch_bounds__(256) void transpose_kernel(
    const float* __restrict__ src, u16* __restrict__ dst, int K, int N) {
    __shared__ u16 t[64][72];
    const int tid = threadIdx.x;
    src += (size_t)blockIdx.z * K * N;
    dst += (size_t)blockIdx.z * K * N;
    const int n0 = blockIdx.x * 64, k0 = blockIdx.y * 64;
    {
        int r = tid >> 2, cq = (tid & 3) * 16;
        const float* sp = src + (size_t)(k0 + r) * N + n0 + cq;
#pragma unroll
        for (int q = 0; q < 4; ++q) {
            float4 v = *reinterpret_cast<const float4*>(sp + q * 4);
            t[r][cq + q * 4 + 0] = f2bf(v.x);
            t[r][cq + q * 4 + 1] = f2bf(v.y);
            t[r][cq + q * 4 + 2] = f2bf(v.z);
            t[r][cq + q * 4 + 3] = f2bf(v.w);
        }
    }
    __syncthreads();
    {
        int rn = tid >> 2, cq = (tid & 3) * 16;
        s16x8 o0, o1;
#pragma unroll
        for (int j = 0; j < 8; ++j) o0[j] = (short)t[cq + j][rn];
#pragma unroll
        for (int j = 0; j < 8; ++j) o1[j] = (short)t[cq + 8 + j][rn];
        u16* dp = dst + (size_t)(n0 + rn) * K + k0 + cq;
        *reinterpret_cast<s16x8*>(dp) = o0;
        *reinterpret_cast<s16x8*>(dp + 8) = o1;
    }
}

// ---------------- input projection: out = x @ W + b + pe (f32 + bf16 mirror) ---
__global__ __launch_bounds__(256) void in_proj_kernel(
    const float* __restrict__ x, const float* __restrict__ W,
    const float* __restrict__ bias, const float* __restrict__ pe,
    float* __restrict__ out, u16* __restrict__ outb) {
    int idx = blockIdx.x * 256 + threadIdx.x;      // over B*S*D
    int d = idx & (ND - 1);
    int bs = idx / ND;
    int s = bs & (NS - 1);
    const float* xr = x + (size_t)bs * NIN;
    float acc = bias[d] + pe[(size_t)s * ND + d];
#pragma unroll
    for (int i = 0; i < NIN; ++i) acc += xr[i] * W[(size_t)i * ND + d];
    out[idx] = acc;
    outb[idx] = f2bf(acc);
}

// ---------------- shared bf16-MFMA GEMM core: 128 x BN tile, BK=64 -------------
template <int BN>
__device__ inline void gemm_core(const u16* __restrict__ A, const u16* __restrict__ Wt,
                                 int K, int bm, int bn, char* lds, int tid,
                                 f32x4 (&acc)[4][BN / 32]) {
    constexpr int NT = BN / 32;
    constexpr int ASZ = 128 * 128;
    constexpr int BSZ = BN * 128;
    const int wid = tid >> 6, lane = tid & 63;
    const int l15 = lane & 15, lhi = lane >> 4;
    const int wr = wid >> 1, wc = wid & 1;

    auto stage = [&](int buf, int k0) {
#pragma unroll
        for (int i = 0; i < 4; ++i) {
            int slot = (wid * 4 + i) * 64 + lane;
            int r = slot >> 3, p = slot & 7;
            const char* src = (const char*)(A + (size_t)(bm + r) * K + k0)
                              + ((p * 16) ^ ((r & 7) << 4));
            GLOAD_LDS16(src, lds + buf * ASZ + (wid * 4 + i) * 1024);
        }
#pragma unroll
        for (int i = 0; i < BN / 32; ++i) {
            int slot = (wid * (BN / 32) + i) * 64 + lane;
            int r = slot >> 3, p = slot & 7;
            const char* src = (const char*)(Wt + (size_t)(bn + r) * K + k0)
                              + ((p * 16) ^ ((r & 7) << 4));
            GLOAD_LDS16(src, lds + 2 * ASZ + buf * BSZ + (wid * (BN / 32) + i) * 1024);
        }
    };

#pragma unroll
    for (int mt = 0; mt < 4; ++mt)
#pragma unroll
        for (int nt = 0; nt < NT; ++nt) acc[mt][nt] = f32x4{0.f, 0.f, 0.f, 0.f};

    const int KT = K >> 6;
    stage(0, 0);
    __syncthreads();
    for (int t = 0; t < KT; ++t) {
        if (t + 1 < KT) stage((t + 1) & 1, (t + 1) << 6);
        const char* Ab = lds + (t & 1) * ASZ;
        const char* Bb = lds + 2 * ASZ + (t & 1) * BSZ;
#pragma unroll
        for (int sl = 0; sl < 2; ++sl) {
            s16x8 af[4];
#pragma unroll
            for (int mt = 0; mt < 4; ++mt) {
                int row = wr * 64 + mt * 16 + l15;
                af[mt] = *reinterpret_cast<const s16x8*>(
                    Ab + ((row * 128 + sl * 64 + lhi * 16) ^ ((row & 7) << 4)));
            }
            s16x8 bfr[NT];
#pragma unroll
            for (int nt = 0; nt < NT; ++nt) {
                int row = wc * (BN / 2) + nt * 16 + l15;
                bfr[nt] = *reinterpret_cast<const s16x8*>(
                    Bb + ((row * 128 + sl * 64 + lhi * 16) ^ ((row & 7) << 4)));
            }
#pragma unroll
            for (int mt = 0; mt < 4; ++mt)
#pragma unroll
                for (int nt = 0; nt < NT; ++nt)
                    acc[mt][nt] = MFMA_BF16(af[mt], bfr[nt], acc[mt][nt]);
        }
        __syncthreads();
    }
}

// ---------------- dual-stream GEMM: z selects stream -------------------------
// OMODE: 0 f32 out; 1 bf16 out + relu; 2 bf16 out
template <int OMODE, int BN>
__global__ __launch_bounds__(256) void bgemm2_kernel(
    const u16* __restrict__ a0, const u16* __restrict__ a1,
    const u16* __restrict__ wt0, const u16* __restrict__ wt1,
    const float* __restrict__ bias0, const float* __restrict__ bias1,
    void* __restrict__ Cv, int M, int N, int K) {
    constexpr int NT = BN / 32;
    __shared__ char lds[2 * 128 * 128 + 2 * BN * 128];
    const int tid = threadIdx.x, z = blockIdx.z;
    const int bm = blockIdx.y * 128, bn = blockIdx.x * BN;
    const u16* A = z ? a1 : a0;
    const u16* Wt = z ? wt1 : wt0;
    const float* bias = z ? bias1 : bias0;

    f32x4 acc[4][NT];
    gemm_core<BN>(A, Wt, K, bm, bn, lds, tid, acc);

    const int wid = tid >> 6, lane = tid & 63;
    const int l15 = lane & 15, lhi = lane >> 4;
    const int wr = wid >> 1, wc = wid & 1;
    float bv[NT];
#pragma unroll
    for (int nt = 0; nt < NT; ++nt) bv[nt] = bias[bn + wc * (BN / 2) + nt * 16 + l15];

    if (OMODE == 0) {
        float* C = (float*)Cv + (size_t)z * M * N;
#pragma unroll
        for (int mt = 0; mt < 4; ++mt) {
            int m0 = bm + wr * 64 + mt * 16 + lhi * 4;
#pragma unroll
            for (int nt = 0; nt < NT; ++nt) {
                int n = bn + wc * (BN / 2) + nt * 16 + l15;
#pragma unroll
                for (int r = 0; r < 4; ++r)
                    C[(size_t)(m0 + r) * N + n] = acc[mt][nt][r] + bv[nt];
            }
        }
    } else {
        u16* C = (u16*)Cv + (size_t)z * M * N;
#pragma unroll
        for (int mt = 0; mt < 4; ++mt) {
            int m0 = bm + wr * 64 + mt * 16 + lhi * 4;
#pragma unroll
            for (int nt = 0; nt < NT; ++nt) {
                int n = bn + wc * (BN / 2) + nt * 16 + l15;
#pragma unroll
                for (int r = 0; r < 4; ++r) {
                    float v = acc[mt][nt][r] + bv[nt];
                    if (OMODE == 1) v = fmaxf(v, 0.f);
                    C[(size_t)(m0 + r) * N + n] = f2bf(v);
                }
            }
        }
    }
}

// ---------------- fused dual-stream QKV projection ---------------------------
// grid (3*8, 32, 2): proj = x>>3 (0=Q rowmajor, 1=K rowmajor, 2=V transposed)
__global__ __launch_bounds__(256) void bgemm_qkv_kernel(
    const u16* __restrict__ aq0, const u16* __restrict__ aq1,
    const u16* __restrict__ akv0, const u16* __restrict__ akv1,
    const u16* __restrict__ wt0, const u16* __restrict__ wt1,
    const float* __restrict__ bb0, const float* __restrict__ bb1,
    u16* __restrict__ Qo, u16* __restrict__ Ko, u16* __restrict__ Vto) {
    __shared__ char lds[2 * 128 * 128 + 2 * 64 * 128];
    const int tid = threadIdx.x, z = blockIdx.z;
    const int proj = blockIdx.x >> 3;
    const int bm = blockIdx.y * 128, bn = (blockIdx.x & 7) * 64;
    const int M = NB * NS;
    const u16* A = (proj == 0) ? (z ? aq1 : aq0) : (z ? akv1 : akv0);
    const u16* Wt = (z ? wt1 : wt0) + (size_t)proj * ND * ND;
    const float* bias = (z ? bb1 : bb0) + proj * ND;

    f32x4 acc[4][2];
    gemm_core<64>(A, Wt, ND, bm, bn, lds, tid, acc);

    const int wid = tid >> 6, lane = tid & 63;
    const int l15 = lane & 15, lhi = lane >> 4;
    const int wr = wid >> 1, wc = wid & 1;
    float bv[2];
#pragma unroll
    for (int nt = 0; nt < 2; ++nt) bv[nt] = bias[bn + wc * 32 + nt * 16 + l15];

    if (proj < 2) {
        u16* C = (proj ? Ko : Qo) + (size_t)z * M * ND;
#pragma unroll
        for (int mt = 0; mt < 4; ++mt) {
            int m0 = bm + wr * 64 + mt * 16 + lhi * 4;
#pragma unroll
            for (int nt = 0; nt < 2; ++nt) {
                int n = bn + wc * 32 + nt * 16 + l15;
#pragma unroll
                for (int r = 0; r < 4; ++r)
                    C[(size_t)(m0 + r) * ND + n] = f2bf(acc[mt][nt][r] + bv[nt]);
            }
        }
    } else {
        // Vt[((b'*NH + h)*NDK + dk)*NS + s], b' = z*4 + m0>>10
#pragma unroll
        for (int mt = 0; mt < 4; ++mt) {
            int m0 = bm + wr * 64 + mt * 16 + lhi * 4;
            int b = (z * M + m0) >> 10, s = m0 & (NS - 1);
#pragma unroll
            for (int nt = 0; nt < 2; ++nt) {
                int n = bn + wc * 32 + nt * 16 + l15;
                int h = n >> 6, dk = n & 63;
                u16x4 o = {f2bf(acc[mt][nt][0] + bv[nt]), f2bf(acc[mt][nt][1] + bv[nt]),
                           f2bf(acc[mt][nt][2] + bv[nt]), f2bf(acc[mt][nt][3] + bv[nt])};
                *reinterpret_cast<u16x4*>(Vto + ((size_t)((b * NH + h) * NDK + dk)) * NS + s) = o;
            }
        }
    }
}

// ---------------- dual-stream residual + LayerNorm ----------------------------
__global__ __launch_bounds__(256) void ln2_kernel(
    const float* __restrict__ x, const float* __restrict__ res,
    const float* __restrict__ g0, const float* __restrict__ g1,
    const float* __restrict__ be0, const float* __restrict__ be1,
    float* __restrict__ outf, u16* __restrict__ outb) {
    int row = blockIdx.x;                 // 0..8191, stream = row>>12
    const float* g = (row >> 12) ? g1 : g0;
    const float* be = (row >> 12) ? be1 : be0;
    int tid = threadIdx.x;
    const float* xr = x + (size_t)row * ND;
    const float* rr = res + (size_t)row * ND;
    float v0 = xr[tid] + rr[tid];
    float v1 = xr[tid + 256] + rr[tid + 256];
    float s = v0 + v1, sq = v0 * v0 + v1 * v1;
#pragma unroll
    for (int m = 1; m < 64; m <<= 1) { s += __shfl_xor(s, m); sq += __shfl_xor(sq, m); }
    __shared__ float ls[4], lq[4];
    int wid = tid >> 6, lane = tid & 63;
    if (lane == 0) { ls[wid] = s; lq[wid] = sq; }
    __syncthreads();
    s = ls[0] + ls[1] + ls[2] + ls[3];
    sq = lq[0] + lq[1] + lq[2] + lq[3];
    float mean = s * (1.f / ND);
    float var = sq * (1.f / ND) - mean * mean;
    float rstd = rsqrtf(var + LN_EPS);
    float o0 = (v0 - mean) * rstd * g[tid] + be[tid];
    float o1 = (v1 - mean) * rstd * g[tid + 256] + be[tid + 256];
    outf[(size_t)row * ND + tid] = o0;
    outf[(size_t)row * ND + tid + 256] = o1;
    outb[(size_t)row * ND + tid] = f2bf(o0);
    outb[(size_t)row * ND + tid + 256] = f2bf(o1);
}

// ---------------- flash attention, bf16 MFMA (batch = 2 streams x B) ----------
// Q,K bf16 [8,S,D]; Vt bf16 [8*H,DK,S]; O bf16 [8,S,D]; grid (S/64, 64)
__global__ __launch_bounds__(256) void attn_kernel(
    const u16* __restrict__ Qb, const u16* __restrict__ Kb,
    const u16* __restrict__ Vtb, u16* __restrict__ O) {
    __shared__ u16 Ks[64 * 64];
    __shared__ u16 Vts[64 * 64];
    __shared__ u16 Ps[4][16 * 64];

    const int tid = threadIdx.x;
    const int w = tid >> 6, lane = tid & 63;
    const int l15 = lane & 15, lhi = lane >> 4;
    const int bh = blockIdx.y;
    const int b = bh >> 3, h = bh & 7;
    const int qb = blockIdx.x * 64 + w * 16;

    s16x8 qf[2];
    {
        const u16* qp = Qb + ((size_t)(b * NS) + qb + l15) * ND + h * NDK + lhi * 8;
        qf[0] = *reinterpret_cast<const s16x8*>(qp);
        qf[1] = *reinterpret_cast<const s16x8*>(qp + 32);
    }

    f32x4 o[4] = {f32x4{0.f, 0.f, 0.f, 0.f}, f32x4{0.f, 0.f, 0.f, 0.f},
                  f32x4{0.f, 0.f, 0.f, 0.f}, f32x4{0.f, 0.f, 0.f, 0.f}};
    float m[4] = {-1e30f, -1e30f, -1e30f, -1e30f};
    float lsum[4] = {0.f, 0.f, 0.f, 0.f};

    const u16* Kbase = Kb + ((size_t)(b * NS)) * ND + h * NDK;
    const u16* Vbase = Vtb + ((size_t)bh * NDK) * NS;

    for (int c = 0; c < NS / 64; ++c) {
        const int kv0 = c * 64;
        __syncthreads();
#pragma unroll
        for (int ss = 0; ss < 2; ++ss) {
            int s = tid + ss * 256;
            int r = s >> 3, c8 = s & 7;
            u32x4 kv = *reinterpret_cast<const u32x4*>(
                Kbase + (size_t)(kv0 + r) * ND + c8 * 8);
            *reinterpret_cast<u32x4*>((char*)Ks +
                ((r * 128 + c8 * 16) ^ ((r & 7) << 4))) = kv;
            u32x4 vv = *reinterpret_cast<const u32x4*>(
                Vbase + (size_t)r * NS + kv0 + c8 * 8);
            *reinterpret_cast<u32x4*>((char*)Vts +
                ((r * 128 + c8 * 16) ^ ((r & 7) << 4))) = vv;
        }
        __syncthreads();

        f32x4 sc[4] = {f32x4{0.f, 0.f, 0.f, 0.f}, f32x4{0.f, 0.f, 0.f, 0.f},
                       f32x4{0.f, 0.f, 0.f, 0.f}, f32x4{0.f, 0.f, 0.f, 0.f}};
#pragma unroll
        for (int sl = 0; sl < 2; ++sl) {
#pragma unroll
            for (int kb = 0; kb < 4; ++kb) {
                int krow = kb * 16 + l15;
                s16x8 kf = *reinterpret_cast<const s16x8*>((char*)Ks +
                    ((krow * 128 + sl * 64 + lhi * 16) ^ ((krow & 7) << 4)));
                sc[kb] = MFMA_BF16(qf[sl], kf, sc[kb]);
            }
        }
        float corr[4];
#pragma unroll
        for (int r = 0; r < 4; ++r) {
            float s0 = sc[0][r] * 0.125f, s1 = sc[1][r] * 0.125f;
            float s2 = sc[2][r] * 0.125f, s3 = sc[3][r] * 0.125f;
            float mx = fmaxf(fmaxf(s0, s1), fmaxf(s2, s3));
#pragma unroll
            for (int msk = 1; msk < 16; msk <<= 1) mx = fmaxf(mx, __shfl_xor(mx, msk));
            float mn = fmaxf(m[r], mx);
            corr[r] = __expf(m[r] - mn);
            m[r] = mn;
            float p0 = __expf(s0 - mn), p1 = __expf(s1 - mn);
            float p2 = __expf(s2 - mn), p3 = __expf(s3 - mn);
            sc[0][r] = p0; sc[1][r] = p1; sc[2][r] = p2; sc[3][r] = p3;
            float rs = p0 + p1 + p2 + p3;
#pragma unroll
            for (int msk = 1; msk < 16; msk <<= 1) rs += __shfl_xor(rs, msk);
            lsum[r] = lsum[r] * corr[r] + rs;
        }
#pragma unroll
        for (int r = 0; r < 4; ++r) {
            int row = lhi * 4 + r;
#pragma unroll
            for (int kb = 0; kb < 4; ++kb) {
                int col = kb * 16 + l15;
                *reinterpret_cast<u16*>((char*)(Ps[w]) +
                    ((row * 128 + col * 2) ^ ((row & 7) << 4))) = f2bf(sc[kb][r]);
            }
        }
#pragma unroll
        for (int db = 0; db < 4; ++db)
#pragma unroll
            for (int r = 0; r < 4; ++r) o[db][r] *= corr[r];
        s16x8 pf[2];
#pragma unroll
        for (int sl = 0; sl < 2; ++sl)
            pf[sl] = *reinterpret_cast<const s16x8*>((char*)(Ps[w]) +
                ((l15 * 128 + sl * 64 + lhi * 16) ^ ((l15 & 7) << 4)));
#pragma unroll
        for (int sl = 0; sl < 2; ++sl) {
#pragma unroll
            for (int db = 0; db < 4; ++db) {
                int vr = db * 16 + l15;
                s16x8 vf = *reinterpret_cast<const s16x8*>((char*)Vts +
                    ((vr * 128 + sl * 64 + lhi * 16) ^ ((vr & 7) << 4)));
                o[db] = MFMA_BF16(pf[sl], vf, o[db]);
            }
        }
    }
#pragma unroll
    for (int db = 0; db < 4; ++db) {
#pragma unroll
        for (int r = 0; r < 4; ++r) {
            int q = qb + lhi * 4 + r;
            O[((size_t)(b * NS) + q) * ND + h * NDK + db * 16 + l15] =
                f2bf(o[db][r] / lsum[r]);
        }
    }
}

// ---------------- mean pool over seq, concat ----------------
__global__ __launch_bounds__(256) void pool_kernel(
    const float* __restrict__ Lb, const float* __restrict__ Rb,
    float* __restrict__ fused) {
    int idx = blockIdx.x * 256 + threadIdx.x;   // B * 2D = 4096
    int b = idx >> 10;
    int c = idx & 1023;
    const float* src = (c < ND) ? (Lb + ((size_t)b * NS) * ND + c)
                                : (Rb + ((size_t)b * NS) * ND + (c - ND));
    float s = 0.f;
    for (int t = 0; t < NS; ++t) s += src[(size_t)t * ND];
    fused[idx] = s * (1.f / NS);
}

// ---------------- heads: hidden = relu(fused @ w1 + b1) ----------------------
// grid (8, 8): x = b*2 + head, y = 64-col chunk
__global__ __launch_bounds__(256) void head_hidden_kernel(
    const float* __restrict__ fused,
    const float* __restrict__ w1a, const float* __restrict__ b1a,
    const float* __restrict__ w1b, const float* __restrict__ b1b,
    float* __restrict__ hid) {
    const int b = blockIdx.x >> 1, head = blockIdx.x & 1;
    const float* w1 = head ? w1b : w1a;
    const float* b1 = head ? b1b : b1a;
    const int tid = threadIdx.x;
    const int j = blockIdx.y * 64 + (tid & 63);
    const int kq = tid >> 6;
    const float* fr = fused + (size_t)b * (2 * ND);
    float p = 0.f;
    for (int k = kq * 256; k < kq * 256 + 256; ++k)
        p += fr[k] * w1[(size_t)k * ND + j];
    __shared__ float part[4][64];
    part[kq][tid & 63] = p;
    __syncthreads();
    if (tid < 64) {
        float v = part[0][tid] + part[1][tid] + part[2][tid] + part[3][tid] + b1[j];
        hid[(size_t)blockIdx.x * ND + j] = fmaxf(v, 0.f);
    }
}

// grid (8): x = b*2 + head; out[head*8 + b*2 + c]
__global__ __launch_bounds__(256) void head_out_kernel(
    const float* __restrict__ hid,
    const float* __restrict__ w2a, const float* __restrict__ b2a,
    const float* __restrict__ w2b, const float* __restrict__ b2b,
    float* __restrict__ out) {
    const int b = blockIdx.x >> 1, head = blockIdx.x & 1;
    const float* w2 = head ? w2b : w2a;
    const float* b2 = head ? b2b : b2a;
    const int tid = threadIdx.x;
    const float* hr = hid + (size_t)blockIdx.x * ND;
    float h0 = hr[tid], h1 = hr[tid + 256];
    float p0 = h0 * w2[tid * 2 + 0] + h1 * w2[(tid + 256) * 2 + 0];
    float p1 = h0 * w2[tid * 2 + 1] + h1 * w2[(tid + 256) * 2 + 1];
#pragma unroll
    for (int m = 1; m < 64; m <<= 1) { p0 += __shfl_xor(p0, m); p1 += __shfl_xor(p1, m); }
    __shared__ float r0s[4], r1s[4];
    int wid = tid >> 6, lane = tid & 63;
    if (lane == 0) { r0s[wid] = p0; r1s[wid] = p1; }
    __syncthreads();
    if (tid == 0) {
        out[head * 8 + b * 2 + 0] = r0s[0] + r0s[1] + r0s[2] + r0s[3] + b2[0];
        out[head * 8 + b * 2 + 1] = r1s[0] + r1s[1] + r1s[2] + r1s[3] + b2[1];
    }
}

extern "C" void kernel_launch(void* const* d_in, const int* in_sizes, int n_in,
                              void* d_out, int out_size, void* d_ws, size_t ws_size,
                              hipStream_t stream) {
    const float* left_wrist  = (const float*)d_in[0];
    const float* right_wrist = (const float*)d_in[1];
    const float* Wl = (const float*)d_in[2];
    const float* bl = (const float*)d_in[3];
    const float* Wr = (const float*)d_in[4];
    const float* br = (const float*)d_in[5];
    const float* pe = (const float*)d_in[6];
    const float* mha_w    = (const float*)d_in[7];   // [L,4,4,D,D]
    const float* mha_b    = (const float*)d_in[8];   // [L,4,4,D]
    const float* mha_ln_g = (const float*)d_in[9];   // [L,4,D]
    const float* mha_ln_b = (const float*)d_in[10];
    const float* ff_w1 = (const float*)d_in[11];     // [L,2,D,F]
    const float* ff_b1 = (const float*)d_in[12];     // [L,2,F]
    const float* ff_w2 = (const float*)d_in[13];     // [L,2,F,D]
    const float* ff_b2 = (const float*)d_in[14];     // [L,2,D]
    const float* ff_ln_g = (const float*)d_in[15];   // [L,2,D]
    const float* ff_ln_b = (const float*)d_in[16];
    const float* h1_w1 = (const float*)d_in[17];
    const float* h1_b1 = (const float*)d_in[18];
    const float* h1_w2 = (const float*)d_in[19];
    const float* h1_b2 = (const float*)d_in[20];
    const float* h2_w1 = (const float*)d_in[21];
    const float* h2_b1 = (const float*)d_in[22];
    const float* h2_w2 = (const float*)d_in[23];
    const float* h2_b2 = (const float*)d_in[24];
    float* out = (float*)d_out;

    const size_t NTOK = (size_t)NB * NS * ND;        // 2M elements per stream
    const int M = NB * NS;                            // 4096 rows per stream
    float* ws = (float*)d_ws;
    // f32 buffers (each 2 streams = 4M floats)
    float* RES   = ws;                  // residual stream [2,B,S,D]
    float* CRES  = RES + 2 * NTOK;      // cross-attn LN out (residual for self)
    float* TMPf  = CRES + 2 * NTOK;     // pre-LN GEMM f32 out
    float* FUSED = TMPf + 2 * NTOK;     // 4096
    float* HID   = FUSED + NB * 2 * ND; // 8 x 512
    // bf16 buffers
    u16* Xbf  = (u16*)(HID + 8 * ND);   // current stream bf16 [2,B,S,D]
    u16* CXbf = Xbf + 2 * NTOK;
    u16* Qbf  = CXbf + 2 * NTOK;
    u16* Kbf  = Qbf + 2 * NTOK;
    u16* Vtbf = Kbf + 2 * NTOK;
    u16* CTbf = Vtbf + 2 * NTOK;
    u16* Hh   = Qbf;                    // FFN hidden aliases Q/K/Vt/CT (dead then)
    u16* WtM  = CTbf + 2 * NTOK;        // 64 x [512,512]
    u16* WtF1 = WtM + (size_t)64 * ND * ND;
    u16* WtF2 = WtF1 + (size_t)8 * ND * NF;

    const size_t DD = (size_t)ND * ND;

    // ---- weight prep ----
    transpose_kernel<<<dim3(ND / 64, ND / 64, 64), 256, 0, stream>>>(mha_w, WtM, ND, ND);
    transpose_kernel<<<dim3(NF / 64, ND / 64, 8), 256, 0, stream>>>(ff_w1, WtF1, ND, NF);
    transpose_kernel<<<dim3(ND / 64, NF / 64, 8), 256, 0, stream>>>(ff_w2, WtF2, NF, ND);

    in_proj_kernel<<<(NB * NS * ND) / 256, 256, 0, stream>>>(left_wrist, Wl, bl, pe, RES, Xbf);
    in_proj_kernel<<<(NB * NS * ND) / 256, 256, 0, stream>>>(right_wrist, Wr, br, pe,
                                                             RES + NTOK, Xbf + NTOK);

    for (int l = 0; l < NLAYERS; ++l) {
        const u16* wt0 = WtM + ((size_t)l * 4 + 0) * 4 * DD;
        const u16* wt1 = WtM + ((size_t)l * 4 + 1) * 4 * DD;
        const u16* wt2 = WtM + ((size_t)l * 4 + 2) * 4 * DD;
        const u16* wt3 = WtM + ((size_t)l * 4 + 3) * 4 * DD;
        const float* bb0 = mha_b + ((size_t)l * 4 + 0) * 4 * ND;
        const float* bb1 = mha_b + ((size_t)l * 4 + 1) * 4 * ND;
        const float* bb2 = mha_b + ((size_t)l * 4 + 2) * 4 * ND;
        const float* bb3 = mha_b + ((size_t)l * 4 + 3) * 4 * ND;

        // ---- cross attention (left queries right, right queries left) ----
        bgemm_qkv_kernel<<<dim3(24, 32, 2), 256, 0, stream>>>(
            Xbf, Xbf + NTOK, Xbf + NTOK, Xbf, wt0, wt1, bb0, bb1, Qbf, Kbf, Vtbf);
        attn_kernel<<<dim3(NS / 64, 2 * NB * NH), 256, 0, stream>>>(Qbf, Kbf, Vtbf, CTbf);
        bgemm2_kernel<0, 64><<<dim3(8, 32, 2), 256, 0, stream>>>(
            CTbf, CTbf + NTOK, wt0 + 3 * DD, wt1 + 3 * DD, bb0 + 3 * ND, bb1 + 3 * ND,
            TMPf, M, ND, ND);
        ln2_kernel<<<2 * M, 256, 0, stream>>>(
            TMPf, RES, mha_ln_g + ((size_t)l * 4 + 0) * ND, mha_ln_g + ((size_t)l * 4 + 1) * ND,
            mha_ln_b + ((size_t)l * 4 + 0) * ND, mha_ln_b + ((size_t)l * 4 + 1) * ND,
            CRES, CXbf);

        // ---- self attention ----
        bgemm_qkv_kernel<<<dim3(24, 32, 2), 256, 0, stream>>>(
            CXbf, CXbf + NTOK, CXbf, CXbf + NTOK, wt2, wt3, bb2, bb3, Qbf, Kbf, Vtbf);
        attn_kernel<<<dim3(NS / 64, 2 * NB * NH), 256, 0, stream>>>(Qbf, Kbf, Vtbf, CTbf);
        bgemm2_kernel<0, 64><<<dim3(8, 32, 2), 256, 0, stream>>>(
            CTbf, CTbf + NTOK, wt2 + 3 * DD, wt3 + 3 * DD, bb2 + 3 * ND, bb3 + 3 * ND,
            TMPf, M, ND, ND);
        ln2_kernel<<<2 * M, 256, 0, stream>>>(
            TMPf, CRES, mha_ln_g + ((size_t)l * 4 + 2) * ND, mha_ln_g + ((size_t)l * 4 + 3) * ND,
            mha_ln_b + ((size_t)l * 4 + 2) * ND, mha_ln_b + ((size_t)l * 4 + 3) * ND,
            RES, Xbf);

        // ---- FFN (both channels batched) ----
        bgemm2_kernel<1, 128><<<dim3(16, 32, 2), 256, 0, stream>>>(
            Xbf, Xbf + NTOK, WtF1 + ((size_t)l * 2 + 0) * ND * NF, WtF1 + ((size_t)l * 2 + 1) * ND * NF,
            ff_b1 + ((size_t)l * 2 + 0) * NF, ff_b1 + ((size_t)l * 2 + 1) * NF,
            Hh, M, NF, ND);
        bgemm2_kernel<0, 64><<<dim3(8, 32, 2), 256, 0, stream>>>(
            Hh, Hh + (size_t)M * NF, WtF2 + ((size_t)l * 2 + 0) * NF * ND, WtF2 + ((size_t)l * 2 + 1) * NF * ND,
            ff_b2 + ((size_t)l * 2 + 0) * ND, ff_b2 + ((size_t)l * 2 + 1) * ND,
            TMPf, M, ND, NF);
        ln2_kernel<<<2 * M, 256, 0, stream>>>(
            TMPf, RES, ff_ln_g + ((size_t)l * 2 + 0) * ND, ff_ln_g + ((size_t)l * 2 + 1) * ND,
            ff_ln_b + ((size_t)l * 2 + 0) * ND, ff_ln_b + ((size_t)l * 2 + 1) * ND,
            RES, Xbf);
    }

    pool_kernel<<<(NB * 2 * ND) / 256, 256, 0, stream>>>(RES, RES + NTOK, FUSED);
    head_hidden_kernel<<<dim3(8, 8), 256, 0, stream>>>(FUSED, h1_w1, h1_b1, h2_w1, h2_b1, HID);
    head_out_kernel<<<8, 256, 0, stream>>>(HID, h1_w2, h1_b2, h2_w2, h2_b2, out);
}

// Round 5
// 1347.484 us; speedup vs baseline: 16.1808x; 1.0982x over previous
//
#include <hip/hip_runtime.h>
#include <hip/hip_bf16.h>

#define NB 4
#define NS 1024
#define NIN 6
#define ND 512
#define NH 8
#define NLAYERS 4
#define NF 2048
#define NDK 64
#define LN_EPS 1e-5f

typedef unsigned short u16;
typedef __attribute__((ext_vector_type(4))) unsigned short u16x4;
typedef __attribute__((ext_vector_type(8))) short s16x8;     // 8 bf16 (4 VGPRs)
typedef __attribute__((ext_vector_type(4))) float f32x4;
typedef __attribute__((ext_vector_type(4))) unsigned int u32x4;

#define MFMA_BF16(A, B, C) __builtin_amdgcn_mfma_f32_16x16x32_bf16(A, B, C, 0, 0, 0)

#define GLOAD_LDS16(gsrc, ldst)                                                  \
    __builtin_amdgcn_global_load_lds(                                            \
        (const __attribute__((address_space(1))) void*)(gsrc),                   \
        (__attribute__((address_space(3))) void*)(ldst), 16, 0, 0)

__device__ inline u16 f2bf(float f) {
    unsigned int u = __builtin_bit_cast(unsigned int, f);
    u += 0x7fffu + ((u >> 16) & 1u);   // round-nearest-even
    return (u16)(u >> 16);
}

// ---------------- weight prep: W[K,N] f32 -> Wt[N,K] bf16 (batched via z) ------
__global__ __launch_bounds__(256) void transpose_kernel(
    const float* __restrict__ src, u16* __restrict__ dst, int K, int N) {
    __shared__ u16 t[64][72];
    const int tid = threadIdx.x;
    src += (size_t)blockIdx.z * K * N;
    dst += (size_t)blockIdx.z * K * N;
    const int n0 = blockIdx.x * 64, k0 = blockIdx.y * 64;
    {
        int r = tid >> 2, cq = (tid & 3) * 16;
        const float* sp = src + (size_t)(k0 + r) * N + n0 + cq;
#pragma unroll
        for (int q = 0; q < 4; ++q) {
            float4 v = *reinterpret_cast<const float4*>(sp + q * 4);
            t[r][cq + q * 4 + 0] = f2bf(v.x);
            t[r][cq + q * 4 + 1] = f2bf(v.y);
            t[r][cq + q * 4 + 2] = f2bf(v.z);
            t[r][cq + q * 4 + 3] = f2bf(v.w);
        }
    }
    __syncthreads();
    {
        int rn = tid >> 2, cq = (tid & 3) * 16;
        s16x8 o0, o1;
#pragma unroll
        for (int j = 0; j < 8; ++j) o0[j] = (short)t[cq + j][rn];
#pragma unroll
        for (int j = 0; j < 8; ++j) o1[j] = (short)t[cq + 8 + j][rn];
        u16* dp = dst + (size_t)(n0 + rn) * K + k0 + cq;
        *reinterpret_cast<s16x8*>(dp) = o0;
        *reinterpret_cast<s16x8*>(dp + 8) = o1;
    }
}

// ---------------- input projection: out = x @ W + b + pe (f32 + bf16 mirror) ---
__global__ __launch_bounds__(256) void in_proj_kernel(
    const float* __restrict__ x, const float* __restrict__ W,
    const float* __restrict__ bias, const float* __restrict__ pe,
    float* __restrict__ out, u16* __restrict__ outb) {
    int idx = blockIdx.x * 256 + threadIdx.x;      // over B*S*D
    int d = idx & (ND - 1);
    int bs = idx / ND;
    int s = bs & (NS - 1);
    const float* xr = x + (size_t)bs * NIN;
    float acc = bias[d] + pe[(size_t)s * ND + d];
#pragma unroll
    for (int i = 0; i < NIN; ++i) acc += xr[i] * W[(size_t)i * ND + d];
    out[idx] = acc;
    outb[idx] = f2bf(acc);
}

// ---------------- shared bf16-MFMA GEMM core: 128 x BN tile, BK=64 -------------
template <int BN>
__device__ inline void gemm_core(const u16* __restrict__ A, const u16* __restrict__ Wt,
                                 int K, int bm, int bn, char* lds, int tid,
                                 f32x4 (&acc)[4][BN / 32]) {
    constexpr int NT = BN / 32;
    constexpr int ASZ = 128 * 128;
    constexpr int BSZ = BN * 128;
    const int wid = tid >> 6, lane = tid & 63;
    const int l15 = lane & 15, lhi = lane >> 4;
    const int wr = wid >> 1, wc = wid & 1;

    auto stage = [&](int buf, int k0) {
#pragma unroll
        for (int i = 0; i < 4; ++i) {
            int slot = (wid * 4 + i) * 64 + lane;
            int r = slot >> 3, p = slot & 7;
            const char* src = (const char*)(A + (size_t)(bm + r) * K + k0)
                              + ((p * 16) ^ ((r & 7) << 4));
            GLOAD_LDS16(src, lds + buf * ASZ + (wid * 4 + i) * 1024);
        }
#pragma unroll
        for (int i = 0; i < BN / 32; ++i) {
            int slot = (wid * (BN / 32) + i) * 64 + lane;
            int r = slot >> 3, p = slot & 7;
            const char* src = (const char*)(Wt + (size_t)(bn + r) * K + k0)
                              + ((p * 16) ^ ((r & 7) << 4));
            GLOAD_LDS16(src, lds + 2 * ASZ + buf * BSZ + (wid * (BN / 32) + i) * 1024);
        }
    };

#pragma unroll
    for (int mt = 0; mt < 4; ++mt)
#pragma unroll
        for (int nt = 0; nt < NT; ++nt) acc[mt][nt] = f32x4{0.f, 0.f, 0.f, 0.f};

    const int KT = K >> 6;
    stage(0, 0);
    __syncthreads();
    for (int t = 0; t < KT; ++t) {
        if (t + 1 < KT) stage((t + 1) & 1, (t + 1) << 6);
        const char* Ab = lds + (t & 1) * ASZ;
        const char* Bb = lds + 2 * ASZ + (t & 1) * BSZ;
#pragma unroll
        for (int sl = 0; sl < 2; ++sl) {
            s16x8 af[4];
#pragma unroll
            for (int mt = 0; mt < 4; ++mt) {
                int row = wr * 64 + mt * 16 + l15;
                af[mt] = *reinterpret_cast<const s16x8*>(
                    Ab + ((row * 128 + sl * 64 + lhi * 16) ^ ((row & 7) << 4)));
            }
            s16x8 bfr[NT];
#pragma unroll
            for (int nt = 0; nt < NT; ++nt) {
                int row = wc * (BN / 2) + nt * 16 + l15;
                bfr[nt] = *reinterpret_cast<const s16x8*>(
                    Bb + ((row * 128 + sl * 64 + lhi * 16) ^ ((row & 7) << 4)));
            }
#pragma unroll
            for (int mt = 0; mt < 4; ++mt)
#pragma unroll
                for (int nt = 0; nt < NT; ++nt)
                    acc[mt][nt] = MFMA_BF16(af[mt], bfr[nt], acc[mt][nt]);
        }
        __syncthreads();
    }
}

// ---------------- dual-stream GEMM: z selects stream -------------------------
// OMODE: 0 f32 out; 1 bf16 out + relu; 2 bf16 out
template <int OMODE, int BN>
__global__ __launch_bounds__(256) void bgemm2_kernel(
    const u16* __restrict__ a0, const u16* __restrict__ a1,
    const u16* __restrict__ wt0, const u16* __restrict__ wt1,
    const float* __restrict__ bias0, const float* __restrict__ bias1,
    void* __restrict__ Cv, int M, int N, int K) {
    constexpr int NT = BN / 32;
    __shared__ char lds[2 * 128 * 128 + 2 * BN * 128];
    const int tid = threadIdx.x, z = blockIdx.z;
    const int bm = blockIdx.y * 128, bn = blockIdx.x * BN;
    const u16* A = z ? a1 : a0;
    const u16* Wt = z ? wt1 : wt0;
    const float* bias = z ? bias1 : bias0;

    f32x4 acc[4][NT];
    gemm_core<BN>(A, Wt, K, bm, bn, lds, tid, acc);

    const int wid = tid >> 6, lane = tid & 63;
    const int l15 = lane & 15, lhi = lane >> 4;
    const int wr = wid >> 1, wc = wid & 1;
    float bv[NT];
#pragma unroll
    for (int nt = 0; nt < NT; ++nt) bv[nt] = bias[bn + wc * (BN / 2) + nt * 16 + l15];

    if (OMODE == 0) {
        float* C = (float*)Cv + (size_t)z * M * N;
#pragma unroll
        for (int mt = 0; mt < 4; ++mt) {
            int m0 = bm + wr * 64 + mt * 16 + lhi * 4;
#pragma unroll
            for (int nt = 0; nt < NT; ++nt) {
                int n = bn + wc * (BN / 2) + nt * 16 + l15;
#pragma unroll
                for (int r = 0; r < 4; ++r)
                    C[(size_t)(m0 + r) * N + n] = acc[mt][nt][r] + bv[nt];
            }
        }
    } else {
        u16* C = (u16*)Cv + (size_t)z * M * N;
#pragma unroll
        for (int mt = 0; mt < 4; ++mt) {
            int m0 = bm + wr * 64 + mt * 16 + lhi * 4;
#pragma unroll
            for (int nt = 0; nt < NT; ++nt) {
                int n = bn + wc * (BN / 2) + nt * 16 + l15;
#pragma unroll
                for (int r = 0; r < 4; ++r) {
                    float v = acc[mt][nt][r] + bv[nt];
                    if (OMODE == 1) v = fmaxf(v, 0.f);
                    C[(size_t)(m0 + r) * N + n] = f2bf(v);
                }
            }
        }
    }
}

// ---------------- fused dual-stream QKV projection ---------------------------
// grid (3*8, 32, 2): proj = x>>3 (0=Q rowmajor, 1=K rowmajor, 2=V transposed)
__global__ __launch_bounds__(256) void bgemm_qkv_kernel(
    const u16* __restrict__ aq0, const u16* __restrict__ aq1,
    const u16* __restrict__ akv0, const u16* __restrict__ akv1,
    const u16* __restrict__ wt0, const u16* __restrict__ wt1,
    const float* __restrict__ bb0, const float* __restrict__ bb1,
    u16* __restrict__ Qo, u16* __restrict__ Ko, u16* __restrict__ Vto) {
    __shared__ char lds[2 * 128 * 128 + 2 * 64 * 128];
    const int tid = threadIdx.x, z = blockIdx.z;
    const int proj = blockIdx.x >> 3;
    const int bm = blockIdx.y * 128, bn = (blockIdx.x & 7) * 64;
    const int M = NB * NS;
    const u16* A = (proj == 0) ? (z ? aq1 : aq0) : (z ? akv1 : akv0);
    const u16* Wt = (z ? wt1 : wt0) + (size_t)proj * ND * ND;
    const float* bias = (z ? bb1 : bb0) + proj * ND;

    f32x4 acc[4][2];
    gemm_core<64>(A, Wt, ND, bm, bn, lds, tid, acc);

    const int wid = tid >> 6, lane = tid & 63;
    const int l15 = lane & 15, lhi = lane >> 4;
    const int wr = wid >> 1, wc = wid & 1;
    float bv[2];
#pragma unroll
    for (int nt = 0; nt < 2; ++nt) bv[nt] = bias[bn + wc * 32 + nt * 16 + l15];

    if (proj < 2) {
        u16* C = (proj ? Ko : Qo) + (size_t)z * M * ND;
#pragma unroll
        for (int mt = 0; mt < 4; ++mt) {
            int m0 = bm + wr * 64 + mt * 16 + lhi * 4;
#pragma unroll
            for (int nt = 0; nt < 2; ++nt) {
                int n = bn + wc * 32 + nt * 16 + l15;
#pragma unroll
                for (int r = 0; r < 4; ++r)
                    C[(size_t)(m0 + r) * ND + n] = f2bf(acc[mt][nt][r] + bv[nt]);
            }
        }
    } else {
        // Vt[((b'*NH + h)*NDK + dk)*NS + s], b' = z*4 + m0>>10
#pragma unroll
        for (int mt = 0; mt < 4; ++mt) {
            int m0 = bm + wr * 64 + mt * 16 + lhi * 4;
            int b = (z * M + m0) >> 10, s = m0 & (NS - 1);
#pragma unroll
            for (int nt = 0; nt < 2; ++nt) {
                int n = bn + wc * 32 + nt * 16 + l15;
                int h = n >> 6, dk = n & 63;
                u16x4 o = {f2bf(acc[mt][nt][0] + bv[nt]), f2bf(acc[mt][nt][1] + bv[nt]),
                           f2bf(acc[mt][nt][2] + bv[nt]), f2bf(acc[mt][nt][3] + bv[nt])};
                *reinterpret_cast<u16x4*>(Vto + ((size_t)((b * NH + h) * NDK + dk)) * NS + s) = o;
            }
        }
    }
}

// ---------------- dual-stream residual + LayerNorm ----------------------------
__global__ __launch_bounds__(256) void ln2_kernel(
    const float* __restrict__ x, const float* __restrict__ res,
    const float* __restrict__ g0, const float* __restrict__ g1,
    const float* __restrict__ be0, const float* __restrict__ be1,
    float* __restrict__ outf, u16* __restrict__ outb) {
    int row = blockIdx.x;                 // 0..8191, stream = row>>12
    const float* g = (row >> 12) ? g1 : g0;
    const float* be = (row >> 12) ? be1 : be0;
    int tid = threadIdx.x;
    const float* xr = x + (size_t)row * ND;
    const float* rr = res + (size_t)row * ND;
    float v0 = xr[tid] + rr[tid];
    float v1 = xr[tid + 256] + rr[tid + 256];
    float s = v0 + v1, sq = v0 * v0 + v1 * v1;
#pragma unroll
    for (int m = 1; m < 64; m <<= 1) { s += __shfl_xor(s, m); sq += __shfl_xor(sq, m); }
    __shared__ float ls[4], lq[4];
    int wid = tid >> 6, lane = tid & 63;
    if (lane == 0) { ls[wid] = s; lq[wid] = sq; }
    __syncthreads();
    s = ls[0] + ls[1] + ls[2] + ls[3];
    sq = lq[0] + lq[1] + lq[2] + lq[3];
    float mean = s * (1.f / ND);
    float var = sq * (1.f / ND) - mean * mean;
    float rstd = rsqrtf(var + LN_EPS);
    float o0 = (v0 - mean) * rstd * g[tid] + be[tid];
    float o1 = (v1 - mean) * rstd * g[tid + 256] + be[tid + 256];
    outf[(size_t)row * ND + tid] = o0;
    outf[(size_t)row * ND + tid + 256] = o1;
    outb[(size_t)row * ND + tid] = f2bf(o0);
    outb[(size_t)row * ND + tid + 256] = f2bf(o1);
}

// ---------------- flash attention, bf16 MFMA, swapped-QK^T softmax ------------
// Q,K bf16 [8,S,D]; Vt bf16 [8*H,DK,S]; O bf16 [8,S,D]; grid (S/64, 64)
// KVBLK=128. Swapped QK: sc = mfma(K, Q) -> D[kv][q], lane owns row q = lane&15.
__global__ __launch_bounds__(256) void attn_kernel(
    const u16* __restrict__ Qb, const u16* __restrict__ Kb,
    const u16* __restrict__ Vtb, u16* __restrict__ O) {
    __shared__ u16 Ks[128 * 64];       // [kv][d] swizzled, 16 KB
    __shared__ u16 Vts[64 * 128];      // [d][kv] swizzled, 16 KB
    __shared__ u16 Ps[4][16 * 128];    // per-wave P [q][kv] swizzled, 16 KB

    const int tid = threadIdx.x;
    const int w = tid >> 6, lane = tid & 63;
    const int l15 = lane & 15, lhi = lane >> 4;
    const int bh = blockIdx.y;
    const int b = bh >> 3, h = bh & 7;
    const int qb = blockIdx.x * 64 + w * 16;

    s16x8 qf[2];
    {
        const u16* qp = Qb + ((size_t)(b * NS) + qb + l15) * ND + h * NDK + lhi * 8;
        qf[0] = *reinterpret_cast<const s16x8*>(qp);
        qf[1] = *reinterpret_cast<const s16x8*>(qp + 32);
    }

    f32x4 o[4] = {f32x4{0.f, 0.f, 0.f, 0.f}, f32x4{0.f, 0.f, 0.f, 0.f},
                  f32x4{0.f, 0.f, 0.f, 0.f}, f32x4{0.f, 0.f, 0.f, 0.f}};
    float m = -1e30f;       // running max for q-row = l15
    float lsum = 0.f;       // running denom for q-row = l15

    const u16* Kbase = Kb + ((size_t)(b * NS)) * ND + h * NDK;
    const u16* Vbase = Vtb + ((size_t)bh * NDK) * NS;

    for (int c = 0; c < NS / 128; ++c) {
        const int kv0 = c * 128;
        __syncthreads();
#pragma unroll
        for (int i = 0; i < 4; ++i) {
            int s = i * 256 + tid;
            {   // K: 128 rows x 128B
                int r = s >> 3, p = s & 7;
                u32x4 kv = *reinterpret_cast<const u32x4*>(
                    Kbase + (size_t)(kv0 + r) * ND + p * 8);
                *reinterpret_cast<u32x4*>((char*)Ks +
                    ((r * 128 + p * 16) ^ ((r & 7) << 4))) = kv;
            }
            {   // V: 64 rows x 256B
                int r = s >> 4, p = s & 15;
                u32x4 vv = *reinterpret_cast<const u32x4*>(
                    Vbase + (size_t)r * NS + kv0 + p * 8);
                *reinterpret_cast<u32x4*>((char*)Vts +
                    ((r * 256 + p * 16) ^ ((r & 7) << 4))) = vv;
            }
        }
        __syncthreads();

        // ---- S^T = K @ Q^T : sc[blk] holds S[kv=blk*16+lhi*4+r][q=l15] ----
        f32x4 sc[8];
#pragma unroll
        for (int blk = 0; blk < 8; ++blk) sc[blk] = f32x4{0.f, 0.f, 0.f, 0.f};
#pragma unroll
        for (int sl = 0; sl < 2; ++sl) {
#pragma unroll
            for (int blk = 0; blk < 8; ++blk) {
                int krow = blk * 16 + l15;
                s16x8 kf = *reinterpret_cast<const s16x8*>((char*)Ks +
                    ((krow * 128 + sl * 64 + lhi * 16) ^ ((krow & 7) << 4)));
                sc[blk] = MFMA_BF16(kf, qf[sl], sc[blk]);
            }
        }
        // ---- online softmax: lane owns q-row l15; 32 local scores ----
        float mx = -1e30f;
#pragma unroll
        for (int blk = 0; blk < 8; ++blk) {
#pragma unroll
            for (int r = 0; r < 4; ++r) {
                float v = sc[blk][r] * 0.125f;
                sc[blk][r] = v;
                mx = fmaxf(mx, v);
            }
        }
        mx = fmaxf(mx, __shfl_xor(mx, 16));
        mx = fmaxf(mx, __shfl_xor(mx, 32));
        float mn = fmaxf(m, mx);
        float corr = __expf(m - mn);
        m = mn;
        float rs = 0.f;
#pragma unroll
        for (int blk = 0; blk < 8; ++blk) {
#pragma unroll
            for (int r = 0; r < 4; ++r) {
                float p = __expf(sc[blk][r] - mn);
                sc[blk][r] = p;
                rs += p;
            }
        }
        rs += __shfl_xor(rs, 16);
        rs += __shfl_xor(rs, 32);
        lsum = lsum * corr + rs;
        // ---- P -> bf16 -> per-wave LDS (packed 8B stores; kv r=0..3 contiguous) ----
#pragma unroll
        for (int blk = 0; blk < 8; ++blk) {
            u16x4 pk = {f2bf(sc[blk][0]), f2bf(sc[blk][1]),
                        f2bf(sc[blk][2]), f2bf(sc[blk][3])};
            *reinterpret_cast<u16x4*>((char*)(Ps[w]) +
                ((l15 * 256 + blk * 32 + lhi * 8) ^ ((l15 & 7) << 4))) = pk;
        }
        // ---- rescale O (O rows q = lhi*4 + r -> fetch corr from lane l15==q) ----
        float cO[4];
#pragma unroll
        for (int r = 0; r < 4; ++r) cO[r] = __shfl(corr, lhi * 4 + r);
#pragma unroll
        for (int db = 0; db < 4; ++db)
#pragma unroll
            for (int r = 0; r < 4; ++r) o[db][r] *= cO[r];
        // ---- PV: A = P (row q=l15), B = V (col d=l15) ----
#pragma unroll
        for (int sl2 = 0; sl2 < 4; ++sl2) {
            s16x8 pf = *reinterpret_cast<const s16x8*>((char*)(Ps[w]) +
                ((l15 * 256 + sl2 * 64 + lhi * 16) ^ ((l15 & 7) << 4)));
#pragma unroll
            for (int db = 0; db < 4; ++db) {
                int vr = db * 16 + l15;
                s16x8 vf = *reinterpret_cast<const s16x8*>((char*)Vts +
                    ((vr * 256 + sl2 * 64 + lhi * 16) ^ ((vr & 7) << 4)));
                o[db] = MFMA_BF16(pf, vf, o[db]);
            }
        }
    }
    float lsO[4];
#pragma unroll
    for (int r = 0; r < 4; ++r) lsO[r] = __shfl(lsum, lhi * 4 + r);
#pragma unroll
    for (int db = 0; db < 4; ++db) {
#pragma unroll
        for (int r = 0; r < 4; ++r) {
            int q = qb + lhi * 4 + r;
            O[((size_t)(b * NS) + q) * ND + h * NDK + db * 16 + l15] =
                f2bf(o[db][r] / lsO[r]);
        }
    }
}

// ---------------- mean pool (two-stage: partial sums + atomicAdd) -------------
// grid (4, 2, 8): b, half(left/right), seq-chunk of 128
__global__ __launch_bounds__(256) void pool2_kernel(
    const float* __restrict__ RES, float* __restrict__ fused) {
    const int b = blockIdx.x, half = blockIdx.y, sc = blockIdx.z;
    const size_t NTOK = (size_t)NB * NS * ND;
    const float* src = RES + (half ? NTOK : 0) + ((size_t)(b * NS + sc * 128)) * ND;
    const int tid = threadIdx.x;
#pragma unroll
    for (int cc = 0; cc < 2; ++cc) {
        int c = cc * 256 + tid;
        float s = 0.f;
        for (int r = 0; r < 128; ++r) s += src[(size_t)r * ND + c];
        atomicAdd(&fused[b * 1024 + half * 512 + c], s * (1.f / NS));
    }
}

// ---------------- heads: hidden = relu(fused @ w1 + b1) ----------------------
// grid (8, 8): x = b*2 + head, y = 64-col chunk
__global__ __launch_bounds__(256) void head_hidden_kernel(
    const float* __restrict__ fused,
    const float* __restrict__ w1a, const float* __restrict__ b1a,
    const float* __restrict__ w1b, const float* __restrict__ b1b,
    float* __restrict__ hid) {
    const int b = blockIdx.x >> 1, head = blockIdx.x & 1;
    const float* w1 = head ? w1b : w1a;
    const float* b1 = head ? b1b : b1a;
    const int tid = threadIdx.x;
    const int j = blockIdx.y * 64 + (tid & 63);
    const int kq = tid >> 6;
    const float* fr = fused + (size_t)b * (2 * ND);
    float p = 0.f;
    for (int k = kq * 256; k < kq * 256 + 256; ++k)
        p += fr[k] * w1[(size_t)k * ND + j];
    __shared__ float part[4][64];
    part[kq][tid & 63] = p;
    __syncthreads();
    if (tid < 64) {
        float v = part[0][tid] + part[1][tid] + part[2][tid] + part[3][tid] + b1[j];
        hid[(size_t)blockIdx.x * ND + j] = fmaxf(v, 0.f);
    }
}

// grid (8): x = b*2 + head; out[head*8 + b*2 + c]
__global__ __launch_bounds__(256) void head_out_kernel(
    const float* __restrict__ hid,
    const float* __restrict__ w2a, const float* __restrict__ b2a,
    const float* __restrict__ w2b, const float* __restrict__ b2b,
    float* __restrict__ out) {
    const int b = blockIdx.x >> 1, head = blockIdx.x & 1;
    const float* w2 = head ? w2b : w2a;
    const float* b2 = head ? b2b : b2a;
    const int tid = threadIdx.x;
    const float* hr = hid + (size_t)blockIdx.x * ND;
    float h0 = hr[tid], h1 = hr[tid + 256];
    float p0 = h0 * w2[tid * 2 + 0] + h1 * w2[(tid + 256) * 2 + 0];
    float p1 = h0 * w2[tid * 2 + 1] + h1 * w2[(tid + 256) * 2 + 1];
#pragma unroll
    for (int m = 1; m < 64; m <<= 1) { p0 += __shfl_xor(p0, m); p1 += __shfl_xor(p1, m); }
    __shared__ float r0s[4], r1s[4];
    int wid = tid >> 6, lane = tid & 63;
    if (lane == 0) { r0s[wid] = p0; r1s[wid] = p1; }
    __syncthreads();
    if (tid == 0) {
        out[head * 8 + b * 2 + 0] = r0s[0] + r0s[1] + r0s[2] + r0s[3] + b2[0];
        out[head * 8 + b * 2 + 1] = r1s[0] + r1s[1] + r1s[2] + r1s[3] + b2[1];
    }
}

extern "C" void kernel_launch(void* const* d_in, const int* in_sizes, int n_in,
                              void* d_out, int out_size, void* d_ws, size_t ws_size,
                              hipStream_t stream) {
    const float* left_wrist  = (const float*)d_in[0];
    const float* right_wrist = (const float*)d_in[1];
    const float* Wl = (const float*)d_in[2];
    const float* bl = (const float*)d_in[3];
    const float* Wr = (const float*)d_in[4];
    const float* br = (const float*)d_in[5];
    const float* pe = (const float*)d_in[6];
    const float* mha_w    = (const float*)d_in[7];   // [L,4,4,D,D]
    const float* mha_b    = (const float*)d_in[8];   // [L,4,4,D]
    const float* mha_ln_g = (const float*)d_in[9];   // [L,4,D]
    const float* mha_ln_b = (const float*)d_in[10];
    const float* ff_w1 = (const float*)d_in[11];     // [L,2,D,F]
    const float* ff_b1 = (const float*)d_in[12];     // [L,2,F]
    const float* ff_w2 = (const float*)d_in[13];     // [L,2,F,D]
    const float* ff_b2 = (const float*)d_in[14];     // [L,2,D]
    const float* ff_ln_g = (const float*)d_in[15];   // [L,2,D]
    const float* ff_ln_b = (const float*)d_in[16];
    const float* h1_w1 = (const float*)d_in[17];
    const float* h1_b1 = (const float*)d_in[18];
    const float* h1_w2 = (const float*)d_in[19];
    const float* h1_b2 = (const float*)d_in[20];
    const float* h2_w1 = (const float*)d_in[21];
    const float* h2_b1 = (const float*)d_in[22];
    const float* h2_w2 = (const float*)d_in[23];
    const float* h2_b2 = (const float*)d_in[24];
    float* out = (float*)d_out;

    const size_t NTOK = (size_t)NB * NS * ND;        // 2M elements per stream
    const int M = NB * NS;                            // 4096 rows per stream
    float* ws = (float*)d_ws;
    // f32 buffers (each 2 streams = 4M floats)
    float* RES   = ws;                  // residual stream [2,B,S,D]
    float* CRES  = RES + 2 * NTOK;      // cross-attn LN out (residual for self)
    float* TMPf  = CRES + 2 * NTOK;     // pre-LN GEMM f32 out
    float* FUSED = TMPf + 2 * NTOK;     // 4096
    float* HID   = FUSED + NB * 2 * ND; // 8 x 512
    // bf16 buffers
    u16* Xbf  = (u16*)(HID + 8 * ND);   // current stream bf16 [2,B,S,D]
    u16* CXbf = Xbf + 2 * NTOK;
    u16* Qbf  = CXbf + 2 * NTOK;
    u16* Kbf  = Qbf + 2 * NTOK;
    u16* Vtbf = Kbf + 2 * NTOK;
    u16* CTbf = Vtbf + 2 * NTOK;
    u16* Hh   = Qbf;                    // FFN hidden aliases Q/K/Vt/CT (dead then)
    u16* WtM  = CTbf + 2 * NTOK;        // 64 x [512,512]
    u16* WtF1 = WtM + (size_t)64 * ND * ND;
    u16* WtF2 = WtF1 + (size_t)8 * ND * NF;

    const size_t DD = (size_t)ND * ND;

    // ---- weight prep ----
    transpose_kernel<<<dim3(ND / 64, ND / 64, 64), 256, 0, stream>>>(mha_w, WtM, ND, ND);
    transpose_kernel<<<dim3(NF / 64, ND / 64, 8), 256, 0, stream>>>(ff_w1, WtF1, ND, NF);
    transpose_kernel<<<dim3(ND / 64, NF / 64, 8), 256, 0, stream>>>(ff_w2, WtF2, NF, ND);

    in_proj_kernel<<<(NB * NS * ND) / 256, 256, 0, stream>>>(left_wrist, Wl, bl, pe, RES, Xbf);
    in_proj_kernel<<<(NB * NS * ND) / 256, 256, 0, stream>>>(right_wrist, Wr, br, pe,
                                                             RES + NTOK, Xbf + NTOK);

    for (int l = 0; l < NLAYERS; ++l) {
        const u16* wt0 = WtM + ((size_t)l * 4 + 0) * 4 * DD;
        const u16* wt1 = WtM + ((size_t)l * 4 + 1) * 4 * DD;
        const u16* wt2 = WtM + ((size_t)l * 4 + 2) * 4 * DD;
        const u16* wt3 = WtM + ((size_t)l * 4 + 3) * 4 * DD;
        const float* bb0 = mha_b + ((size_t)l * 4 + 0) * 4 * ND;
        const float* bb1 = mha_b + ((size_t)l * 4 + 1) * 4 * ND;
        const float* bb2 = mha_b + ((size_t)l * 4 + 2) * 4 * ND;
        const float* bb3 = mha_b + ((size_t)l * 4 + 3) * 4 * ND;

        // ---- cross attention (left queries right, right queries left) ----
        bgemm_qkv_kernel<<<dim3(24, 32, 2), 256, 0, stream>>>(
            Xbf, Xbf + NTOK, Xbf + NTOK, Xbf, wt0, wt1, bb0, bb1, Qbf, Kbf, Vtbf);
        attn_kernel<<<dim3(NS / 64, 2 * NB * NH), 256, 0, stream>>>(Qbf, Kbf, Vtbf, CTbf);
        bgemm2_kernel<0, 64><<<dim3(8, 32, 2), 256, 0, stream>>>(
            CTbf, CTbf + NTOK, wt0 + 3 * DD, wt1 + 3 * DD, bb0 + 3 * ND, bb1 + 3 * ND,
            TMPf, M, ND, ND);
        ln2_kernel<<<2 * M, 256, 0, stream>>>(
            TMPf, RES, mha_ln_g + ((size_t)l * 4 + 0) * ND, mha_ln_g + ((size_t)l * 4 + 1) * ND,
            mha_ln_b + ((size_t)l * 4 + 0) * ND, mha_ln_b + ((size_t)l * 4 + 1) * ND,
            CRES, CXbf);

        // ---- self attention ----
        bgemm_qkv_kernel<<<dim3(24, 32, 2), 256, 0, stream>>>(
            CXbf, CXbf + NTOK, CXbf, CXbf + NTOK, wt2, wt3, bb2, bb3, Qbf, Kbf, Vtbf);
        attn_kernel<<<dim3(NS / 64, 2 * NB * NH), 256, 0, stream>>>(Qbf, Kbf, Vtbf, CTbf);
        bgemm2_kernel<0, 64><<<dim3(8, 32, 2), 256, 0, stream>>>(
            CTbf, CTbf + NTOK, wt2 + 3 * DD, wt3 + 3 * DD, bb2 + 3 * ND, bb3 + 3 * ND,
            TMPf, M, ND, ND);
        ln2_kernel<<<2 * M, 256, 0, stream>>>(
            TMPf, CRES, mha_ln_g + ((size_t)l * 4 + 2) * ND, mha_ln_g + ((size_t)l * 4 + 3) * ND,
            mha_ln_b + ((size_t)l * 4 + 2) * ND, mha_ln_b + ((size_t)l * 4 + 3) * ND,
            RES, Xbf);

        // ---- FFN (both channels batched) ----
        bgemm2_kernel<1, 128><<<dim3(16, 32, 2), 256, 0, stream>>>(
            Xbf, Xbf + NTOK, WtF1 + ((size_t)l * 2 + 0) * ND * NF, WtF1 + ((size_t)l * 2 + 1) * ND * NF,
            ff_b1 + ((size_t)l * 2 + 0) * NF, ff_b1 + ((size_t)l * 2 + 1) * NF,
            Hh, M, NF, ND);
        bgemm2_kernel<0, 64><<<dim3(8, 32, 2), 256, 0, stream>>>(
            Hh, Hh + (size_t)M * NF, WtF2 + ((size_t)l * 2 + 0) * NF * ND, WtF2 + ((size_t)l * 2 + 1) * NF * ND,
            ff_b2 + ((size_t)l * 2 + 0) * ND, ff_b2 + ((size_t)l * 2 + 1) * ND,
            TMPf, M, ND, NF);
        ln2_kernel<<<2 * M, 256, 0, stream>>>(
            TMPf, RES, ff_ln_g + ((size_t)l * 2 + 0) * ND, ff_ln_g + ((size_t)l * 2 + 1) * ND,
            ff_ln_b + ((size_t)l * 2 + 0) * ND, ff_ln_b + ((size_t)l * 2 + 1) * ND,
            RES, Xbf);
    }

    hipMemsetAsync(FUSED, 0, NB * 2 * ND * sizeof(float), stream);
    pool2_kernel<<<dim3(NB, 2, 8), 256, 0, stream>>>(RES, FUSED);
    head_hidden_kernel<<<dim3(8, 8), 256, 0, stream>>>(FUSED, h1_w1, h1_b1, h2_w1, h2_b1, HID);
    head_out_kernel<<<8, 256, 0, stream>>>(HID, h1_w2, h1_b2, h2_w2, h2_b2, out);
}